// Round 20
// baseline (253.727 us; speedup 1.0000x reference)
//
#include <hip/hip_runtime.h>
#include <hip/hip_bf16.h>
#include <math.h>

// B=2 N=1024 M=512 D=1024 H=16 DH=64 MID=1024 DC=768 MULT=4
// Round-19 base + BK=64 rolled out to QKV / ff1 / cross (fixed-overhead amortization).

typedef float f32x4 __attribute__((ext_vector_type(4)));
typedef __bf16 bf16x8 __attribute__((ext_vector_type(8)));
typedef __bf16 bf16x4 __attribute__((ext_vector_type(4)));
typedef __bf16 bf16x2 __attribute__((ext_vector_type(2)));

#define DEVI __device__ __forceinline__

DEVI void gload16(const void* g, void* l) {
  __builtin_amdgcn_global_load_lds((const __attribute__((address_space(1))) void*)g,
                                   (__attribute__((address_space(3))) void*)l, 16, 0, 0);
}

// exact-GELU via A&S 7.1.26 erf poly (|err|<=1.5e-7, far below bf16 noise)
DEVI float fast_gelu(float x) {
  float a = fabsf(x) * 0.7071067811865475f;
  float tt = 1.0f / (1.0f + 0.3275911f * a);
  float p = tt * (0.254829592f + tt * (-0.284496736f + tt * (1.421413741f +
            tt * (-1.453152027f + tt * 1.061405429f))));
  float er = 1.0f - p * __expf(-a * a);
  er = (x < 0.f) ? -er : er;
  return 0.5f * x * (1.0f + er);
}

// ---------------- fused prep: vectorized transposes (32k x 128n tiles) + rope tbl + mod partials ----
struct WtDesc {
  const float* src[8];
  __bf16* dst[8];
  int K[8], N[8];
  int tstart[9];
};

__global__ __launch_bounds__(256) void prep_kernel(WtDesc d,
                                                   float2* __restrict__ tbl,
                                                   const float* __restrict__ cond,
                                                   const float* __restrict__ g1w,
                                                   const float* __restrict__ b1w,
                                                   const float* __restrict__ g2w,
                                                   const float* __restrict__ b2w,
                                                   float* __restrict__ part) {
  __shared__ float smem[32 * 129];
  int blk = blockIdx.x;
  int wtend = d.tstart[8];
  int t = threadIdx.x;
  if (blk < wtend) {
    int e = 0;
#pragma unroll
    for (int i = 0; i < 7; ++i) e += (blk >= d.tstart[i + 1]) ? 1 : 0;
    int li = blk - d.tstart[e];
    const float* W = d.src[e];
    __bf16* WT = d.dst[e];
    int K = d.K[e], N = d.N[e];
    int ntx = N >> 7;
    int n0 = (li % ntx) * 128, k0 = (li / ntx) * 32;
    int tx = t & 31, ty = t >> 5;
#pragma unroll
    for (int i = 0; i < 4; ++i) {
      int k = ty + i * 8;
      f32x4 v = *(const f32x4*)(W + (size_t)(k0 + k) * N + n0 + tx * 4);
#pragma unroll
      for (int j = 0; j < 4; ++j) smem[k * 129 + tx * 4 + j] = v[j];
    }
    __syncthreads();
    int kc = t & 3;
#pragma unroll
    for (int i = 0; i < 2; ++i) {
      int n = i * 64 + (t >> 2);
      bf16x8 o;
#pragma unroll
      for (int j = 0; j < 8; ++j) o[j] = (__bf16)smem[(kc * 8 + j) * 129 + n];
      *(bf16x8*)(WT + (size_t)(n0 + n) * K + k0 + kc * 8) = o;
    }
  } else if (blk < wtend + 128) {
    int idx = (blk - wtend) * 256 + t;
    int n = idx >> 5, i = idx & 31;
    float inv = expf(-(float)(2 * i) * (1.0f / 64.0f) * 9.210340371976184f);
    float ang = (float)n * inv;
    tbl[idx] = make_float2(sinf(ang), cosf(ang));
  } else {
    int f = blk - wtend - 128;
    int dchunk = f & 3, b = (f >> 2) & 1, z = f >> 3;
    int mat = z >> 3, ks = z & 7;
    const float* W = (mat == 0) ? g1w : (mat == 1) ? b1w : (mat == 2) ? g2w : b2w;
    float* sc = smem;
    if (t < 128) sc[t] = cond[b * 1024 + ks * 128 + t];
    __syncthreads();
    int dd = dchunk * 256 + t;
    const float* Wp = W + (size_t)(ks * 128) * 1024 + dd;
    float acc = 0.f;
#pragma unroll 8
    for (int k = 0; k < 128; ++k) acc += sc[k] * Wp[(size_t)k * 1024];
    part[(size_t)(z * 2 + b) * 1024 + dd] = acc;
  }
}

__global__ __launch_bounds__(256) void mod_reduce_kernel(
    const float* __restrict__ part,
    const float* __restrict__ g1b, const float* __restrict__ b1b,
    const float* __restrict__ g2b, const float* __restrict__ b2b,
    float* __restrict__ mods) {
  int idx = blockIdx.x * 256 + threadIdx.x;
  int mat = idx >> 11, b = (idx >> 10) & 1, d = idx & 1023;
  float s = 0.f;
#pragma unroll
  for (int ks = 0; ks < 8; ++ks) s += part[(size_t)((mat * 8 + ks) * 2 + b) * 1024 + d];
  const float* Bv = (mat == 0) ? g1b : (mat == 1) ? b1b : (mat == 2) ? g2b : b2b;
  mods[(size_t)(mat * 2 + b) * 1024 + d] = s + Bv[d];
}

// ---------------- adaLN (first block only) ----------------
__global__ __launch_bounds__(256) void adaln_kernel(const float* __restrict__ X,
                                                    const float* __restrict__ lnw,
                                                    const float* __restrict__ lnb,
                                                    const float* __restrict__ mods,
                                                    int gi, int bi,
                                                    __bf16* __restrict__ out) {
  __shared__ float red[2][4];
  int row = blockIdx.x;
  int b = row >> 10;
  int t = threadIdx.x;
  const float4 xv = ((const float4*)(X + (size_t)row * 1024))[t];
  float s  = xv.x + xv.y + xv.z + xv.w;
  float s2 = xv.x * xv.x + xv.y * xv.y + xv.z * xv.z + xv.w * xv.w;
  int lane = t & 63, w = t >> 6;
#pragma unroll
  for (int off = 32; off > 0; off >>= 1) {
    s += __shfl_down(s, off);
    s2 += __shfl_down(s2, off);
  }
  if (lane == 0) { red[0][w] = s; red[1][w] = s2; }
  __syncthreads();
  s  = red[0][0] + red[0][1] + red[0][2] + red[0][3];
  s2 = red[1][0] + red[1][1] + red[1][2] + red[1][3];
  float mu = s * (1.0f / 1024.0f);
  float var = s2 * (1.0f / 1024.0f) - mu * mu;
  float rstd = rsqrtf(var + 1e-5f);
  const float4 wv = ((const float4*)lnw)[t];
  const float4 bv = ((const float4*)lnb)[t];
  const float4 gv = ((const float4*)(mods + (size_t)(gi * 2 + b) * 1024))[t];
  const float4 tv = ((const float4*)(mods + (size_t)(bi * 2 + b) * 1024))[t];
  bf16x4 ov;
  ov[0] = (__bf16)(((xv.x - mu) * rstd * wv.x + bv.x) * (1.0f + gv.x) + tv.x);
  ov[1] = (__bf16)(((xv.y - mu) * rstd * wv.y + bv.y) * (1.0f + gv.y) + tv.y);
  ov[2] = (__bf16)(((xv.z - mu) * rstd * wv.z + bv.z) * (1.0f + gv.z) + tv.z);
  ov[3] = (__bf16)(((xv.w - mu) * rstd * wv.w + bv.w) * (1.0f + gv.w) + tv.w);
  *(bf16x4*)(out + (size_t)row * 1024 + t * 4) = ov;
}

// ---------------- fused split-K reduce + bias + residual + adaLN ----------------
__global__ __launch_bounds__(256) void red_adaln_kernel(const float* __restrict__ part,
                                                        const float* __restrict__ bias,
                                                        const float* __restrict__ res,
                                                        const float* __restrict__ lnw,
                                                        const float* __restrict__ lnb,
                                                        const float* __restrict__ mods,
                                                        int gi, int bi, int MN,
                                                        float* __restrict__ xout,
                                                        __bf16* __restrict__ ain) {
  __shared__ float red[2][4];
  int row = blockIdx.x;
  int b = row >> 10;
  int t = threadIdx.x;
  size_t base = (size_t)row * 1024 + t * 4;
  float4 p0 = *(const float4*)(part + base);
  float4 p1 = *(const float4*)(part + MN + base);
  float4 rr = *(const float4*)(res + base);
  float4 bb = ((const float4*)bias)[t];
  float4 y;
  y.x = p0.x + p1.x + bb.x + rr.x;
  y.y = p0.y + p1.y + bb.y + rr.y;
  y.z = p0.z + p1.z + bb.z + rr.z;
  y.w = p0.w + p1.w + bb.w + rr.w;
  *(float4*)(xout + base) = y;
  float s  = y.x + y.y + y.z + y.w;
  float s2 = y.x * y.x + y.y * y.y + y.z * y.z + y.w * y.w;
  int lane = t & 63, w = t >> 6;
#pragma unroll
  for (int off = 32; off > 0; off >>= 1) {
    s += __shfl_down(s, off);
    s2 += __shfl_down(s2, off);
  }
  if (lane == 0) { red[0][w] = s; red[1][w] = s2; }
  __syncthreads();
  s  = red[0][0] + red[0][1] + red[0][2] + red[0][3];
  s2 = red[1][0] + red[1][1] + red[1][2] + red[1][3];
  float mu = s * (1.0f / 1024.0f);
  float var = s2 * (1.0f / 1024.0f) - mu * mu;
  float rstd = rsqrtf(var + 1e-5f);
  const float4 wv = ((const float4*)lnw)[t];
  const float4 bv = ((const float4*)lnb)[t];
  const float4 gv = ((const float4*)(mods + (size_t)(gi * 2 + b) * 1024))[t];
  const float4 tv = ((const float4*)(mods + (size_t)(bi * 2 + b) * 1024))[t];
  bf16x4 ov;
  ov[0] = (__bf16)(((y.x - mu) * rstd * wv.x + bv.x) * (1.0f + gv.x) + tv.x);
  ov[1] = (__bf16)(((y.y - mu) * rstd * wv.y + bv.y) * (1.0f + gv.y) + tv.y);
  ov[2] = (__bf16)(((y.z - mu) * rstd * wv.z + bv.z) * (1.0f + gv.z) + tv.z);
  ov[3] = (__bf16)(((y.w - mu) * rstd * wv.w + bv.w) * (1.0f + gv.w) + tv.w);
  *(bf16x4*)(ain + (size_t)row * 1024 + t * 4) = ov;
}

// ---------------- context LN (D=768) ----------------
__global__ __launch_bounds__(256) void ctxln_kernel(const float* __restrict__ X,
                                                    const float* __restrict__ w,
                                                    const float* __restrict__ bias,
                                                    __bf16* __restrict__ out) {
  __shared__ float red[2][4];
  int row = blockIdx.x;
  int t = threadIdx.x;
  const float* xp = X + (size_t)row * 768;
  float v[3];
  float s = 0.f, s2 = 0.f;
#pragma unroll
  for (int i = 0; i < 3; ++i) {
    v[i] = xp[t + i * 256];
    s += v[i];
    s2 += v[i] * v[i];
  }
  int lane = t & 63, wv_ = t >> 6;
#pragma unroll
  for (int off = 32; off > 0; off >>= 1) {
    s += __shfl_down(s, off);
    s2 += __shfl_down(s2, off);
  }
  if (lane == 0) { red[0][wv_] = s; red[1][wv_] = s2; }
  __syncthreads();
  s  = red[0][0] + red[0][1] + red[0][2] + red[0][3];
  s2 = red[1][0] + red[1][1] + red[1][2] + red[1][3];
  float mu = s * (1.0f / 768.0f);
  float var = s2 * (1.0f / 768.0f) - mu * mu;
  float rstd = rsqrtf(var + 1e-5f);
#pragma unroll
  for (int i = 0; i < 3; ++i) {
    int c = t + i * 256;
    out[(size_t)row * 768 + c] = (__bf16)((v[i] - mu) * rstd * w[c] + bias[c]);
  }
}

// ---------------- V transpose (bf16): Vb[b*Ntok+n][h*64+d] -> VT[bh*64+d][n] ----------------
__global__ __launch_bounds__(256) void vtb_kernel(const __bf16* __restrict__ Vb,
                                                  __bf16* __restrict__ VT, int Ntok) {
  __shared__ __bf16 tile[64][68];
  int bh = blockIdx.x, nt = blockIdx.y;
  int b = bh >> 4, h = bh & 15;
  int t = threadIdx.x;
  int tx = t & 15, ty = t >> 4;
#pragma unroll
  for (int i = 0; i < 4; ++i) {
    int n = ty + i * 16;
    bf16x4 v = *(const bf16x4*)(Vb + (size_t)(b * Ntok + nt * 64 + n) * 1024 + h * 64 + tx * 4);
#pragma unroll
    for (int j = 0; j < 4; ++j) tile[n][tx * 4 + j] = v[j];
  }
  __syncthreads();
#pragma unroll
  for (int i = 0; i < 4; ++i) {
    int d = ty + i * 16;
    bf16x4 o;
#pragma unroll
    for (int j = 0; j < 4; ++j) o[j] = tile[tx * 4 + j][d];
    *(bf16x4*)(VT + ((size_t)bh * 64 + d) * Ntok + nt * 64 + tx * 4) = o;
  }
}

// ---------------- BK=64 GEMM: 128x64 tile, one vmcnt+barrier per 64-wide K-step ----------------
// LDS: chunk c of row r at c^(r&7) (64-col XOR swizzle, verified). NBUF=DEPTH+1.
// EPI: 2 bf16 gelu(acc+bias); 3 fp32 partial at slice z; 4 self-QKV (rope Q,K; V bf16)
template <int EPI, int DEPTH>
__global__ __launch_bounds__(256) void gemm64(const __bf16* __restrict__ A,
                                              const __bf16* __restrict__ BT,
                                              const float* __restrict__ bias,
                                              const float* __restrict__ res,
                                              void* __restrict__ outv,
                                              int M, int N, int K, int kslices,
                                              const float2* __restrict__ tbl,
                                              __bf16* __restrict__ Qro,
                                              __bf16* __restrict__ Kro,
                                              __bf16* __restrict__ Vbo,
                                              int Ntok) {
  constexpr int BM = 128, BN = 64;
  constexpr int NBUF = DEPTH + 1;
  constexpr int LPT = 6;  // 4 A + 2 B gload16 per thread per stage
  __shared__ __bf16 sA[NBUF][BM * 64];
  __shared__ __bf16 sB[NBUF][BN * 64];
  const int t = threadIdx.x;
  const int w = t >> 6, lane = t & 63;
  const int lr = lane & 15, lg = lane >> 4;
  const int sx = lr & 7;
  int nwg = gridDim.x * gridDim.y * gridDim.z;
  int flat = blockIdx.x + gridDim.x * (blockIdx.y + gridDim.y * blockIdx.z);
  flat = (flat & 7) * (nwg >> 3) + (flat >> 3);
  const int bm = flat % gridDim.x;
  int rest = flat / gridDim.x;
  const int bn = rest % gridDim.y;
  const int bz = rest / gridDim.y;
  const int wm = (w >> 1) * 64, wn = (w & 1) * 32;
  const int kper = K / kslices;
  const int k0 = bz * kper;
  const int nsteps = kper / 64;
  f32x4 acc[4][2] = {};

  auto stage = [&](int buf, int kt) {
#pragma unroll
    for (int i = 0; i < 4; ++i) {
      int e8 = i * 256 + t;                  // 1024 chunks: row=e8>>3 (0..127), c=e8&7
      int row = e8 >> 3, c = e8 & 7;
      int scol = (c ^ (row & 7)) << 3;
      gload16(A + (size_t)(bm * BM + row) * K + kt + scol, &sA[buf][e8 * 8]);
    }
#pragma unroll
    for (int i = 0; i < 2; ++i) {
      int e8 = i * 256 + t;                  // 512 chunks: row=e8>>3 (0..63)
      int row = e8 >> 3, c = e8 & 7;
      int scol = (c ^ (row & 7)) << 3;
      gload16(BT + (size_t)(bn * BN + row) * K + kt + scol, &sB[buf][e8 * 8]);
    }
  };

  auto compute = [&](int buf) {
#pragma unroll
    for (int kk = 0; kk < 2; ++kk) {
      bf16x8 af[4], bfr[2];
#pragma unroll
      for (int mi = 0; mi < 4; ++mi)
        af[mi] = *(const bf16x8*)(&sA[buf][(wm + mi * 16 + lr) * 64 + (((kk * 4 + lg) ^ sx) << 3)]);
#pragma unroll
      for (int ni = 0; ni < 2; ++ni)
        bfr[ni] = *(const bf16x8*)(&sB[buf][(wn + ni * 16 + lr) * 64 + (((kk * 4 + lg) ^ sx) << 3)]);
#pragma unroll
      for (int mi = 0; mi < 4; ++mi)
#pragma unroll
        for (int ni = 0; ni < 2; ++ni)
          acc[mi][ni] = __builtin_amdgcn_mfma_f32_16x16x32_bf16(af[mi], bfr[ni], acc[mi][ni], 0, 0, 0);
    }
  };

#pragma unroll
  for (int i = 0; i < DEPTH; ++i) stage(i, k0 + i * 64);

  int it = 0;
  for (; it < nsteps - (DEPTH - 1); ++it) {
    asm volatile("s_waitcnt vmcnt(%0)" :: "n"((DEPTH - 1) * LPT) : "memory");
    __builtin_amdgcn_s_barrier();
    __builtin_amdgcn_sched_barrier(0);
    if (it + DEPTH < nsteps) stage((it + DEPTH) % NBUF, k0 + (it + DEPTH) * 64);
    compute(it % NBUF);
  }
  asm volatile("s_waitcnt vmcnt(0)" ::: "memory");
  __builtin_amdgcn_s_barrier();
  __builtin_amdgcn_sched_barrier(0);
  for (; it < nsteps; ++it) compute(it % NBUF);

#pragma unroll
  for (int mi = 0; mi < 4; ++mi) {
    int row = bm * BM + wm + mi * 16 + lg * 4;
#pragma unroll
    for (int ni = 0; ni < 2; ++ni) {
      int col = bn * BN + wn + ni * 16 + lr;
#pragma unroll
      for (int r = 0; r < 4; ++r) {
        float v = acc[mi][ni][r];
        int erow = row + r;
        size_t off = (size_t)erow * N + col;
        if (EPI == 2) {
          ((__bf16*)outv)[off] = (__bf16)fast_gelu(v + bias[col]);
        } else if (EPI == 3) {
          ((float*)outv)[(size_t)bz * M * N + off] = v;
        } else if (EPI == 4) {
          float ov = __shfl_xor(v, 1);
          int b = erow >> 10, n = erow & 1023;
          if (col < 2048) {
            int h = (col >> 6) & 15, dh = col & 63;
            float2 sc = tbl[n * 32 + (dh >> 1)];
            float rv = (lr & 1) ? (ov * sc.x + v * sc.y) : (v * sc.y - ov * sc.x);
            __bf16* dst;
            if (col < 1024) { rv *= 0.125f; dst = Qro; } else dst = Kro;
            dst[((size_t)(b * 16 + h) * Ntok + n) * 64 + dh] = (__bf16)rv;
          } else {
            Vbo[(size_t)erow * 1024 + (col - 2048)] = (__bf16)v;
          }
        }
      }
    }
  }
}

// ---------------- fused cross-attn projections, BK=64: 512 blocks = cq (256) + ckv (256) ------
__global__ __launch_bounds__(256) void gemm_cross(const __bf16* __restrict__ Aq,
                                                  const __bf16* __restrict__ Bq,
                                                  const __bf16* __restrict__ Akv,
                                                  const __bf16* __restrict__ Bkv,
                                                  const float2* __restrict__ tbl,
                                                  __bf16* __restrict__ Qro,
                                                  __bf16* __restrict__ Kro,
                                                  __bf16* __restrict__ Vbo) {
  constexpr int BM = 128, BN = 64, DEPTH = 2, NBUF = 3, LPT = 6;
  __shared__ __bf16 sA[NBUF][BM * 64];
  __shared__ __bf16 sB[NBUF][BN * 64];
  const int t = threadIdx.x;
  const int w = t >> 6, lane = t & 63;
  const int lr = lane & 15, lg = lane >> 4;
  const int sx = lr & 7;
  int flat = blockIdx.x;
  flat = (flat & 7) * 64 + (flat >> 3);  // bijective XCD swizzle over 512
  const bool isq = flat < 256;
  const __bf16* A  = isq ? Aq : Akv;
  const __bf16* BT = isq ? Bq : Bkv;
  const int K = isq ? 1024 : 768;
  int lf = isq ? flat : flat - 256;
  const int bm = isq ? (lf & 15) : (lf & 7);
  const int bn = isq ? (lf >> 4) : (lf >> 3);
  const int wm = (w >> 1) * 64, wn = (w & 1) * 32;
  const int nsteps = K >> 6;  // 16 or 12
  f32x4 acc[4][2] = {};

  auto stage = [&](int buf, int kt) {
#pragma unroll
    for (int i = 0; i < 4; ++i) {
      int e8 = i * 256 + t;
      int row = e8 >> 3, c = e8 & 7;
      int scol = (c ^ (row & 7)) << 3;
      gload16(A + (size_t)(bm * BM + row) * K + kt + scol, &sA[buf][e8 * 8]);
    }
#pragma unroll
    for (int i = 0; i < 2; ++i) {
      int e8 = i * 256 + t;
      int row = e8 >> 3, c = e8 & 7;
      int scol = (c ^ (row & 7)) << 3;
      gload16(BT + (size_t)(bn * BN + row) * K + kt + scol, &sB[buf][e8 * 8]);
    }
  };

  auto compute = [&](int buf) {
#pragma unroll
    for (int kk = 0; kk < 2; ++kk) {
      bf16x8 af[4], bfr[2];
#pragma unroll
      for (int mi = 0; mi < 4; ++mi)
        af[mi] = *(const bf16x8*)(&sA[buf][(wm + mi * 16 + lr) * 64 + (((kk * 4 + lg) ^ sx) << 3)]);
#pragma unroll
      for (int ni = 0; ni < 2; ++ni)
        bfr[ni] = *(const bf16x8*)(&sB[buf][(wn + ni * 16 + lr) * 64 + (((kk * 4 + lg) ^ sx) << 3)]);
#pragma unroll
      for (int mi = 0; mi < 4; ++mi)
#pragma unroll
        for (int ni = 0; ni < 2; ++ni)
          acc[mi][ni] = __builtin_amdgcn_mfma_f32_16x16x32_bf16(af[mi], bfr[ni], acc[mi][ni], 0, 0, 0);
    }
  };

#pragma unroll
  for (int i = 0; i < DEPTH; ++i) stage(i, i * 64);

  int it = 0;
  for (; it < nsteps - (DEPTH - 1); ++it) {
    asm volatile("s_waitcnt vmcnt(%0)" :: "n"((DEPTH - 1) * LPT) : "memory");
    __builtin_amdgcn_s_barrier();
    __builtin_amdgcn_sched_barrier(0);
    if (it + DEPTH < nsteps) stage((it + DEPTH) % NBUF, (it + DEPTH) * 64);
    compute(it % NBUF);
  }
  asm volatile("s_waitcnt vmcnt(0)" ::: "memory");
  __builtin_amdgcn_s_barrier();
  __builtin_amdgcn_sched_barrier(0);
  for (; it < nsteps; ++it) compute(it % NBUF);

#pragma unroll
  for (int mi = 0; mi < 4; ++mi) {
    int row = bm * 128 + wm + mi * 16 + lg * 4;
#pragma unroll
    for (int ni = 0; ni < 2; ++ni) {
      int col = bn * 64 + wn + ni * 16 + lr;
#pragma unroll
      for (int r = 0; r < 4; ++r) {
        float v = acc[mi][ni][r];
        int erow = row + r;
        float ov = __shfl_xor(v, 1);
        if (isq) {
          int b = erow >> 10, n = erow & 1023;
          int h = col >> 6, dh = col & 63;
          float2 sc = tbl[n * 32 + (dh >> 1)];
          float rv = ((lr & 1) ? (ov * sc.x + v * sc.y) : (v * sc.y - ov * sc.x)) * 0.125f;
          Qro[((size_t)(b * 16 + h) * 1024 + n) * 64 + dh] = (__bf16)rv;
        } else {
          int b = erow >> 9, n = erow & 511;
          if (col < 1024) {
            int h = col >> 6, dh = col & 63;
            float2 sc = tbl[n * 32 + (dh >> 1)];
            float rv = (lr & 1) ? (ov * sc.x + v * sc.y) : (v * sc.y - ov * sc.x);
            Kro[((size_t)(b * 16 + h) * 512 + n) * 64 + dh] = (__bf16)rv;
          } else {
            Vbo[(size_t)erow * 1024 + (col - 1024)] = (__bf16)v;
          }
        }
      }
    }
  }
}

// ---------------- split-K reduce: out = p0+p1+bias+res (final ff2 only) ----------------
__global__ __launch_bounds__(256) void ff2red_kernel(const float* __restrict__ part,
                                                     const float* __restrict__ bias,
                                                     const float* __restrict__ res,
                                                     float* __restrict__ out, int MN, int N) {
  int idx = blockIdx.x * 256 + threadIdx.x;
  float4 p0 = ((const float4*)part)[idx];
  float4 p1 = ((const float4*)(part + MN))[idx];
  float4 rr = ((const float4*)res)[idx];
  int colb = (idx * 4) & (N - 1);
  float4 bb = *(const float4*)(bias + colb);
  float4 o;
  o.x = p0.x + p1.x + bb.x + rr.x;
  o.y = p0.y + p1.y + bb.y + rr.y;
  o.z = p0.z + p1.z + bb.z + rr.z;
  o.w = p0.w + p1.w + bb.w + rr.w;
  ((float4*)out)[idx] = o;
}

// ---------------- attention, LDS-staged K/V, direct normalized bf16 output ----------------
template <int KITERS>
__global__ __launch_bounds__(256) void attn_kernel(const __bf16* __restrict__ Qr,
                                                   const __bf16* __restrict__ Kr,
                                                   const __bf16* __restrict__ VT,
                                                   __bf16* __restrict__ O,
                                                   int Nq, int Nk) {
  __shared__ __bf16 sK[2][64 * 64];
  __shared__ __bf16 sV[2][64 * 64];
  __shared__ __bf16 Pl[4][16 * 64];
  const int t = threadIdx.x, w = t >> 6, lane = t & 63;
  const int lr = lane & 15, lg = lane >> 4;
  const int lsrc = lane & 48;
  const int swz = (lr & 7) << 3;
  int flat = blockIdx.x + (blockIdx.y << 4);  // grid 16x32
  flat = (flat & 7) * 64 + (flat >> 3);
  const int bh = flat >> 4;
  const int q0 = (flat & 15) * 64 + w * 16;
  const int b = bh >> 4, h = bh & 15;

  auto stage = [&](int buf, int kt) {
#pragma unroll
    for (int i = 0; i < 2; ++i) {
      int e8 = i * 256 + t;
      int row = e8 >> 3, col8 = e8 & 7;
      int scol = (col8 ^ (row & 7)) << 3;
      gload16(Kr + ((size_t)bh * Nk + kt + row) * 64 + scol, &sK[buf][e8 * 8]);
      gload16(VT + ((size_t)bh * 64 + row) * Nk + kt + scol, &sV[buf][e8 * 8]);
    }
  };

  bf16x8 qf[2];
#pragma unroll
  for (int kh = 0; kh < 2; ++kh)
    qf[kh] = *(const bf16x8*)(Qr + ((size_t)bh * Nq + q0 + lr) * 64 + kh * 32 + lg * 8);
  f32x4 accO[4] = {};
  float m = -INFINITY, l = 0.f;

  stage(0, 0);
  __syncthreads();
  int cur = 0;
#pragma unroll
  for (int it = 0; it < KITERS; ++it) {
    if (it + 1 < KITERS) stage(cur ^ 1, (it + 1) * 64);
    f32x4 s[4] = {};
#pragma unroll
    for (int nf = 0; nf < 4; ++nf) {
      int r = nf * 16 + lr;
#pragma unroll
      for (int kh = 0; kh < 2; ++kh) {
        bf16x8 kf = *(const bf16x8*)(&sK[cur][r * 64 + (((kh * 4 + lg) ^ (lr & 7)) << 3)]);
        s[nf] = __builtin_amdgcn_mfma_f32_16x16x32_bf16(kf, qf[kh], s[nf], 0, 0, 0);
      }
    }
    float p[16];
#pragma unroll
    for (int j = 0; j < 16; ++j) p[j] = s[j >> 2][j & 3];
    float pm = p[0];
#pragma unroll
    for (int j = 1; j < 16; ++j) pm = fmaxf(pm, p[j]);
    pm = fmaxf(pm, __shfl_xor(pm, 16));
    pm = fmaxf(pm, __shfl_xor(pm, 32));
    if (!__all(pm <= m + 8.f)) {  // defer-max
      float mnew = fmaxf(m, pm);
      float resc = __expf(m - mnew);
      float rq[4];
#pragma unroll
      for (int r = 0; r < 4; ++r) rq[r] = __shfl(resc, lsrc | (lg * 4 + r));
#pragma unroll
      for (int df = 0; df < 4; ++df)
#pragma unroll
        for (int r = 0; r < 4; ++r) accO[df][r] *= rq[r];
      l *= resc;
      m = mnew;
    }
    float rs = 0.f;
#pragma unroll
    for (int j = 0; j < 16; ++j) { p[j] = __expf(p[j] - m); rs += p[j]; }
    rs += __shfl_xor(rs, 16);
    rs += __shfl_xor(rs, 32);
    l += rs;
#pragma unroll
    for (int nf = 0; nf < 4; ++nf)
#pragma unroll
      for (int jj = 0; jj < 2; ++jj) {
        int k = nf * 16 + lg * 4 + 2 * jj;
        bf16x2 pk;
        pk[0] = (__bf16)p[nf * 4 + 2 * jj];
        pk[1] = (__bf16)p[nf * 4 + 2 * jj + 1];
        *(bf16x2*)(&Pl[w][lr * 64 + (k ^ swz)]) = pk;
      }
    bf16x8 pa0 = *(const bf16x8*)(&Pl[w][lr * 64 + ((lg * 8) ^ swz)]);
    bf16x8 pa1 = *(const bf16x8*)(&Pl[w][lr * 64 + ((32 + lg * 8) ^ swz)]);
#pragma unroll
    for (int df = 0; df < 4; ++df) {
      int d = df * 16 + lr;
      bf16x8 vf0 = *(const bf16x8*)(&sV[cur][d * 64 + ((lg ^ (lr & 7)) << 3)]);
      bf16x8 vf1 = *(const bf16x8*)(&sV[cur][d * 64 + (((4 + lg) ^ (lr & 7)) << 3)]);
      accO[df] = __builtin_amdgcn_mfma_f32_16x16x32_bf16(pa0, vf0, accO[df], 0, 0, 0);
      accO[df] = __builtin_amdgcn_mfma_f32_16x16x32_bf16(pa1, vf1, accO[df], 0, 0, 0);
    }
    __syncthreads();
    cur ^= 1;
  }
  float lq[4];
#pragma unroll
  for (int r = 0; r < 4; ++r) lq[r] = __shfl(l, lsrc | (lg * 4 + r));
#pragma unroll
  for (int r = 0; r < 4; ++r) {
    float inv = 1.0f / lq[r];
    int n = q0 + lg * 4 + r;
#pragma unroll
    for (int df = 0; df < 4; ++df)
      O[(size_t)(b * 1024 + n) * 1024 + h * 64 + df * 16 + lr] = (__bf16)(accO[df][r] * inv);
  }
}

extern "C" void kernel_launch(void* const* d_in, const int* in_sizes, int n_in,
                              void* d_out, int out_size, void* d_ws, size_t ws_size,
                              hipStream_t stream) {
  (void)in_sizes; (void)n_in; (void)out_size; (void)ws_size;
  const float* x       = (const float*)d_in[0];
  const float* cond    = (const float*)d_in[1];
  const float* ctx     = (const float*)d_in[2];
  const float* ln1_w   = (const float*)d_in[3];
  const float* ln1_b   = (const float*)d_in[4];
  const float* g1_w    = (const float*)d_in[5];
  const float* g1_b    = (const float*)d_in[6];
  const float* b1_w    = (const float*)d_in[7];
  const float* b1_b    = (const float*)d_in[8];
  const float* ln2_w   = (const float*)d_in[9];
  const float* ln2_b   = (const float*)d_in[10];
  const float* g2_w    = (const float*)d_in[11];
  const float* g2_b    = (const float*)d_in[12];
  const float* b2_w    = (const float*)d_in[13];
  const float* b2_b    = (const float*)d_in[14];
  const float* sa_wq   = (const float*)d_in[15];
  const float* sa_wkv  = (const float*)d_in[16];
  const float* sa_wo   = (const float*)d_in[17];
  const float* sa_bo   = (const float*)d_in[18];
  const float* ca_lnc_w = (const float*)d_in[19];
  const float* ca_lnc_b = (const float*)d_in[20];
  const float* ca_wq   = (const float*)d_in[21];
  const float* ca_wkv  = (const float*)d_in[22];
  const float* ca_wo   = (const float*)d_in[23];
  const float* ca_bo   = (const float*)d_in[24];
  const float* ff_w1   = (const float*)d_in[25];
  const float* ff_b1   = (const float*)d_in[26];
  const float* ff_w2   = (const float*)d_in[27];
  const float* ff_b2   = (const float*)d_in[28];
  float* out = (float*)d_out;

  char* ws = (char*)d_ws;
  size_t o = 0;
  auto alloc = [&](size_t bytes) {
    void* p = ws + o;
    o += (bytes + 255) & ~(size_t)255;
    return p;
  };

  __bf16* wqT   = (__bf16*)alloc(1024ull * 1024 * 2);  // wqT+wkvT contiguous => BT[3072][1024]
  __bf16* wkvT  = (__bf16*)alloc(2048ull * 1024 * 2);
  __bf16* woT   = (__bf16*)alloc(1024ull * 1024 * 2);
  __bf16* cwqT  = (__bf16*)alloc(1024ull * 1024 * 2);
  __bf16* cwkvT = (__bf16*)alloc(2048ull * 768 * 2);
  __bf16* cwoT  = (__bf16*)alloc(1024ull * 1024 * 2);
  __bf16* ff1T  = (__bf16*)alloc(4096ull * 1024 * 2);
  __bf16* ff2T  = (__bf16*)alloc(1024ull * 4096 * 2);
  float*  mods  = (float*)alloc(4ull * 2 * 1024 * 4);
  float2* tbl   = (float2*)alloc(1024ull * 32 * 8);
  __bf16* ain   = (__bf16*)alloc(2048ull * 1024 * 2);
  float*  Qf    = (float*)alloc(2048ull * 1024 * 4);
  float*  KVf   = (float*)alloc(2048ull * 2048 * 4);
  __bf16* ctxn  = (__bf16*)alloc(1024ull * 768 * 2);
  __bf16* Qr    = (__bf16*)alloc(2048ull * 1024 * 2);
  __bf16* Kr    = (__bf16*)alloc(2048ull * 1024 * 2);
  __bf16* VTb   = (__bf16*)alloc(2048ull * 1024 * 2);
  __bf16* Ob    = (__bf16*)alloc(2048ull * 1024 * 2);
  float*  x1    = (float*)alloc(2048ull * 1024 * 4);
  float*  x2    = (float*)alloc(2048ull * 1024 * 4);
  __bf16* hb    = (__bf16*)KVf;   // FFN hidden (2048x4096 bf16)
  float*  pbuf  = (float*)Qr;     // ff2 split-K partials: 2 x 8MB (Qr..Ob dead in FFN)
  float*  wopb  = (float*)KVf;    // wo split-K partials: 2 x 8MB (KVf free during attn phases)
  float*  mpart = (float*)Qf;     // mod GEMV partials (dead after mod_reduce)
  __bf16* Vb    = (__bf16*)Qf;    // V bf16 token-major (written by QKV/ckv epilogues)

  // ---- fused prep (vectorized 32x128 transposes) ----
  WtDesc wd;
  const float* srcs[8] = {sa_wq, sa_wkv, sa_wo, ca_wq, ca_wkv, ca_wo, ff_w1, ff_w2};
  __bf16* dsts[8] = {wqT, wkvT, woT, cwqT, cwkvT, cwoT, ff1T, ff2T};
  int Ks[8] = {1024, 1024, 1024, 1024, 768, 1024, 1024, 4096};
  int Ns[8] = {1024, 2048, 1024, 1024, 2048, 1024, 4096, 1024};
  int cum = 0;
  for (int i = 0; i < 8; ++i) {
    wd.src[i] = srcs[i]; wd.dst[i] = dsts[i]; wd.K[i] = Ks[i]; wd.N[i] = Ns[i];
    wd.tstart[i] = cum;
    cum += (Ks[i] >> 5) * (Ns[i] >> 7);
  }
  wd.tstart[8] = cum;  // 3968
  prep_kernel<<<cum + 128 + 256, 256, 0, stream>>>(wd, tbl, cond, g1_w, b1_w, g2_w, b2_w, mpart);
  mod_reduce_kernel<<<32, 256, 0, stream>>>(mpart, g1_b, b1_b, g2_b, b2_b, mods);

  // ---- self attention ----
  adaln_kernel<<<2048, 256, 0, stream>>>(x, ln1_w, ln1_b, mods, 0, 1, ain);
  gemm64<4, 2><<<dim3(16, 48), 256, 0, stream>>>(ain, wqT, nullptr, nullptr, nullptr,
                                                 2048, 3072, 1024, 1, tbl, Qr, Kr, Vb, 1024);
  vtb_kernel<<<dim3(32, 16), 256, 0, stream>>>(Vb, VTb, 1024);
  attn_kernel<16><<<dim3(16, 32), 256, 0, stream>>>(Qr, Kr, VTb, Ob, 1024, 1024);
  gemm64<3, 2><<<dim3(16, 16, 2), 256, 0, stream>>>(Ob, woT, nullptr, nullptr, wopb,
                                                    2048, 1024, 1024, 2, nullptr, nullptr, nullptr, nullptr, 0);
  red_adaln_kernel<<<2048, 256, 0, stream>>>(wopb, sa_bo, x, ln1_w, ln1_b, mods, 0, 1,
                                             2048 * 1024, x1, ain);

  // ---- cross attention ----
  ctxln_kernel<<<1024, 256, 0, stream>>>(ctx, ca_lnc_w, ca_lnc_b, ctxn);
  gemm_cross<<<512, 256, 0, stream>>>(ain, cwqT, ctxn, cwkvT, tbl, Qr, Kr, Vb);
  vtb_kernel<<<dim3(32, 8), 256, 0, stream>>>(Vb, VTb, 512);
  attn_kernel<8><<<dim3(16, 32), 256, 0, stream>>>(Qr, Kr, VTb, Ob, 1024, 512);
  gemm64<3, 2><<<dim3(16, 16, 2), 256, 0, stream>>>(Ob, cwoT, nullptr, nullptr, wopb,
                                                    2048, 1024, 1024, 2, nullptr, nullptr, nullptr, nullptr, 0);
  red_adaln_kernel<<<2048, 256, 0, stream>>>(wopb, ca_bo, x1, ln2_w, ln2_b, mods, 2, 3,
                                             2048 * 1024, x2, ain);

  // ---- FFN ----
  gemm64<2, 2><<<dim3(16, 64), 256, 0, stream>>>(ain, ff1T, ff_b1, nullptr, hb,
                                                 2048, 4096, 1024, 1, nullptr, nullptr, nullptr, nullptr, 0);
  gemm64<3, 2><<<dim3(16, 16, 2), 256, 0, stream>>>(hb, ff2T, nullptr, nullptr, pbuf,
                                                    2048, 1024, 4096, 2, nullptr, nullptr, nullptr, nullptr, 0);
  ff2red_kernel<<<2048, 256, 0, stream>>>(pbuf, ff_b2, x2, out, 2048 * 1024, 1024);
}

// Round 21
// 237.083 us; speedup vs baseline: 1.0702x; 1.0702x over previous
//
#include <hip/hip_runtime.h>
#include <hip/hip_bf16.h>
#include <math.h>

// B=2 N=1024 M=512 D=1024 H=16 DH=64 MID=1024 DC=768 MULT=4
// Round-20 minus QKV rollback: BK=64 only where grid fits co-residency (<=512 or exact multiple).

typedef float f32x4 __attribute__((ext_vector_type(4)));
typedef __bf16 bf16x8 __attribute__((ext_vector_type(8)));
typedef __bf16 bf16x4 __attribute__((ext_vector_type(4)));
typedef __bf16 bf16x2 __attribute__((ext_vector_type(2)));

#define DEVI __device__ __forceinline__

DEVI void gload16(const void* g, void* l) {
  __builtin_amdgcn_global_load_lds((const __attribute__((address_space(1))) void*)g,
                                   (__attribute__((address_space(3))) void*)l, 16, 0, 0);
}

// exact-GELU via A&S 7.1.26 erf poly (|err|<=1.5e-7, far below bf16 noise)
DEVI float fast_gelu(float x) {
  float a = fabsf(x) * 0.7071067811865475f;
  float tt = 1.0f / (1.0f + 0.3275911f * a);
  float p = tt * (0.254829592f + tt * (-0.284496736f + tt * (1.421413741f +
            tt * (-1.453152027f + tt * 1.061405429f))));
  float er = 1.0f - p * __expf(-a * a);
  er = (x < 0.f) ? -er : er;
  return 0.5f * x * (1.0f + er);
}

// ---------------- fused prep: vectorized transposes (32k x 128n tiles) + rope tbl + mod partials ----
struct WtDesc {
  const float* src[8];
  __bf16* dst[8];
  int K[8], N[8];
  int tstart[9];
};

__global__ __launch_bounds__(256) void prep_kernel(WtDesc d,
                                                   float2* __restrict__ tbl,
                                                   const float* __restrict__ cond,
                                                   const float* __restrict__ g1w,
                                                   const float* __restrict__ b1w,
                                                   const float* __restrict__ g2w,
                                                   const float* __restrict__ b2w,
                                                   float* __restrict__ part) {
  __shared__ float smem[32 * 129];
  int blk = blockIdx.x;
  int wtend = d.tstart[8];
  int t = threadIdx.x;
  if (blk < wtend) {
    int e = 0;
#pragma unroll
    for (int i = 0; i < 7; ++i) e += (blk >= d.tstart[i + 1]) ? 1 : 0;
    int li = blk - d.tstart[e];
    const float* W = d.src[e];
    __bf16* WT = d.dst[e];
    int K = d.K[e], N = d.N[e];
    int ntx = N >> 7;
    int n0 = (li % ntx) * 128, k0 = (li / ntx) * 32;
    int tx = t & 31, ty = t >> 5;
#pragma unroll
    for (int i = 0; i < 4; ++i) {
      int k = ty + i * 8;
      f32x4 v = *(const f32x4*)(W + (size_t)(k0 + k) * N + n0 + tx * 4);
#pragma unroll
      for (int j = 0; j < 4; ++j) smem[k * 129 + tx * 4 + j] = v[j];
    }
    __syncthreads();
    int kc = t & 3;
#pragma unroll
    for (int i = 0; i < 2; ++i) {
      int n = i * 64 + (t >> 2);
      bf16x8 o;
#pragma unroll
      for (int j = 0; j < 8; ++j) o[j] = (__bf16)smem[(kc * 8 + j) * 129 + n];
      *(bf16x8*)(WT + (size_t)(n0 + n) * K + k0 + kc * 8) = o;
    }
  } else if (blk < wtend + 128) {
    int idx = (blk - wtend) * 256 + t;
    int n = idx >> 5, i = idx & 31;
    float inv = expf(-(float)(2 * i) * (1.0f / 64.0f) * 9.210340371976184f);
    float ang = (float)n * inv;
    tbl[idx] = make_float2(sinf(ang), cosf(ang));
  } else {
    int f = blk - wtend - 128;
    int dchunk = f & 3, b = (f >> 2) & 1, z = f >> 3;
    int mat = z >> 3, ks = z & 7;
    const float* W = (mat == 0) ? g1w : (mat == 1) ? b1w : (mat == 2) ? g2w : b2w;
    float* sc = smem;
    if (t < 128) sc[t] = cond[b * 1024 + ks * 128 + t];
    __syncthreads();
    int dd = dchunk * 256 + t;
    const float* Wp = W + (size_t)(ks * 128) * 1024 + dd;
    float acc = 0.f;
#pragma unroll 8
    for (int k = 0; k < 128; ++k) acc += sc[k] * Wp[(size_t)k * 1024];
    part[(size_t)(z * 2 + b) * 1024 + dd] = acc;
  }
}

__global__ __launch_bounds__(256) void mod_reduce_kernel(
    const float* __restrict__ part,
    const float* __restrict__ g1b, const float* __restrict__ b1b,
    const float* __restrict__ g2b, const float* __restrict__ b2b,
    float* __restrict__ mods) {
  int idx = blockIdx.x * 256 + threadIdx.x;
  int mat = idx >> 11, b = (idx >> 10) & 1, d = idx & 1023;
  float s = 0.f;
#pragma unroll
  for (int ks = 0; ks < 8; ++ks) s += part[(size_t)((mat * 8 + ks) * 2 + b) * 1024 + d];
  const float* Bv = (mat == 0) ? g1b : (mat == 1) ? b1b : (mat == 2) ? g2b : b2b;
  mods[(size_t)(mat * 2 + b) * 1024 + d] = s + Bv[d];
}

// ---------------- adaLN (first block only) ----------------
__global__ __launch_bounds__(256) void adaln_kernel(const float* __restrict__ X,
                                                    const float* __restrict__ lnw,
                                                    const float* __restrict__ lnb,
                                                    const float* __restrict__ mods,
                                                    int gi, int bi,
                                                    __bf16* __restrict__ out) {
  __shared__ float red[2][4];
  int row = blockIdx.x;
  int b = row >> 10;
  int t = threadIdx.x;
  const float4 xv = ((const float4*)(X + (size_t)row * 1024))[t];
  float s  = xv.x + xv.y + xv.z + xv.w;
  float s2 = xv.x * xv.x + xv.y * xv.y + xv.z * xv.z + xv.w * xv.w;
  int lane = t & 63, w = t >> 6;
#pragma unroll
  for (int off = 32; off > 0; off >>= 1) {
    s += __shfl_down(s, off);
    s2 += __shfl_down(s2, off);
  }
  if (lane == 0) { red[0][w] = s; red[1][w] = s2; }
  __syncthreads();
  s  = red[0][0] + red[0][1] + red[0][2] + red[0][3];
  s2 = red[1][0] + red[1][1] + red[1][2] + red[1][3];
  float mu = s * (1.0f / 1024.0f);
  float var = s2 * (1.0f / 1024.0f) - mu * mu;
  float rstd = rsqrtf(var + 1e-5f);
  const float4 wv = ((const float4*)lnw)[t];
  const float4 bv = ((const float4*)lnb)[t];
  const float4 gv = ((const float4*)(mods + (size_t)(gi * 2 + b) * 1024))[t];
  const float4 tv = ((const float4*)(mods + (size_t)(bi * 2 + b) * 1024))[t];
  bf16x4 ov;
  ov[0] = (__bf16)(((xv.x - mu) * rstd * wv.x + bv.x) * (1.0f + gv.x) + tv.x);
  ov[1] = (__bf16)(((xv.y - mu) * rstd * wv.y + bv.y) * (1.0f + gv.y) + tv.y);
  ov[2] = (__bf16)(((xv.z - mu) * rstd * wv.z + bv.z) * (1.0f + gv.z) + tv.z);
  ov[3] = (__bf16)(((xv.w - mu) * rstd * wv.w + bv.w) * (1.0f + gv.w) + tv.w);
  *(bf16x4*)(out + (size_t)row * 1024 + t * 4) = ov;
}

// ---------------- fused split-K reduce + bias + residual + adaLN ----------------
__global__ __launch_bounds__(256) void red_adaln_kernel(const float* __restrict__ part,
                                                        const float* __restrict__ bias,
                                                        const float* __restrict__ res,
                                                        const float* __restrict__ lnw,
                                                        const float* __restrict__ lnb,
                                                        const float* __restrict__ mods,
                                                        int gi, int bi, int MN,
                                                        float* __restrict__ xout,
                                                        __bf16* __restrict__ ain) {
  __shared__ float red[2][4];
  int row = blockIdx.x;
  int b = row >> 10;
  int t = threadIdx.x;
  size_t base = (size_t)row * 1024 + t * 4;
  float4 p0 = *(const float4*)(part + base);
  float4 p1 = *(const float4*)(part + MN + base);
  float4 rr = *(const float4*)(res + base);
  float4 bb = ((const float4*)bias)[t];
  float4 y;
  y.x = p0.x + p1.x + bb.x + rr.x;
  y.y = p0.y + p1.y + bb.y + rr.y;
  y.z = p0.z + p1.z + bb.z + rr.z;
  y.w = p0.w + p1.w + bb.w + rr.w;
  *(float4*)(xout + base) = y;
  float s  = y.x + y.y + y.z + y.w;
  float s2 = y.x * y.x + y.y * y.y + y.z * y.z + y.w * y.w;
  int lane = t & 63, w = t >> 6;
#pragma unroll
  for (int off = 32; off > 0; off >>= 1) {
    s += __shfl_down(s, off);
    s2 += __shfl_down(s2, off);
  }
  if (lane == 0) { red[0][w] = s; red[1][w] = s2; }
  __syncthreads();
  s  = red[0][0] + red[0][1] + red[0][2] + red[0][3];
  s2 = red[1][0] + red[1][1] + red[1][2] + red[1][3];
  float mu = s * (1.0f / 1024.0f);
  float var = s2 * (1.0f / 1024.0f) - mu * mu;
  float rstd = rsqrtf(var + 1e-5f);
  const float4 wv = ((const float4*)lnw)[t];
  const float4 bv = ((const float4*)lnb)[t];
  const float4 gv = ((const float4*)(mods + (size_t)(gi * 2 + b) * 1024))[t];
  const float4 tv = ((const float4*)(mods + (size_t)(bi * 2 + b) * 1024))[t];
  bf16x4 ov;
  ov[0] = (__bf16)(((y.x - mu) * rstd * wv.x + bv.x) * (1.0f + gv.x) + tv.x);
  ov[1] = (__bf16)(((y.y - mu) * rstd * wv.y + bv.y) * (1.0f + gv.y) + tv.y);
  ov[2] = (__bf16)(((y.z - mu) * rstd * wv.z + bv.z) * (1.0f + gv.z) + tv.z);
  ov[3] = (__bf16)(((y.w - mu) * rstd * wv.w + bv.w) * (1.0f + gv.w) + tv.w);
  *(bf16x4*)(ain + (size_t)row * 1024 + t * 4) = ov;
}

// ---------------- context LN (D=768) ----------------
__global__ __launch_bounds__(256) void ctxln_kernel(const float* __restrict__ X,
                                                    const float* __restrict__ w,
                                                    const float* __restrict__ bias,
                                                    __bf16* __restrict__ out) {
  __shared__ float red[2][4];
  int row = blockIdx.x;
  int t = threadIdx.x;
  const float* xp = X + (size_t)row * 768;
  float v[3];
  float s = 0.f, s2 = 0.f;
#pragma unroll
  for (int i = 0; i < 3; ++i) {
    v[i] = xp[t + i * 256];
    s += v[i];
    s2 += v[i] * v[i];
  }
  int lane = t & 63, wv_ = t >> 6;
#pragma unroll
  for (int off = 32; off > 0; off >>= 1) {
    s += __shfl_down(s, off);
    s2 += __shfl_down(s2, off);
  }
  if (lane == 0) { red[0][wv_] = s; red[1][wv_] = s2; }
  __syncthreads();
  s  = red[0][0] + red[0][1] + red[0][2] + red[0][3];
  s2 = red[1][0] + red[1][1] + red[1][2] + red[1][3];
  float mu = s * (1.0f / 768.0f);
  float var = s2 * (1.0f / 768.0f) - mu * mu;
  float rstd = rsqrtf(var + 1e-5f);
#pragma unroll
  for (int i = 0; i < 3; ++i) {
    int c = t + i * 256;
    out[(size_t)row * 768 + c] = (__bf16)((v[i] - mu) * rstd * w[c] + bias[c]);
  }
}

// ---------------- V transpose (bf16): Vb[b*Ntok+n][h*64+d] -> VT[bh*64+d][n] ----------------
__global__ __launch_bounds__(256) void vtb_kernel(const __bf16* __restrict__ Vb,
                                                  __bf16* __restrict__ VT, int Ntok) {
  __shared__ __bf16 tile[64][68];
  int bh = blockIdx.x, nt = blockIdx.y;
  int b = bh >> 4, h = bh & 15;
  int t = threadIdx.x;
  int tx = t & 15, ty = t >> 4;
#pragma unroll
  for (int i = 0; i < 4; ++i) {
    int n = ty + i * 16;
    bf16x4 v = *(const bf16x4*)(Vb + (size_t)(b * Ntok + nt * 64 + n) * 1024 + h * 64 + tx * 4);
#pragma unroll
    for (int j = 0; j < 4; ++j) tile[n][tx * 4 + j] = v[j];
  }
  __syncthreads();
#pragma unroll
  for (int i = 0; i < 4; ++i) {
    int d = ty + i * 16;
    bf16x4 o;
#pragma unroll
    for (int j = 0; j < 4; ++j) o[j] = tile[tx * 4 + j][d];
    *(bf16x4*)(VT + ((size_t)bh * 64 + d) * Ntok + nt * 64 + tx * 4) = o;
  }
}

// ---------------- pipelined bf16 GEMM BK=32 (for QKV: 3 blocks/CU at grid 768) ----------------
// EPI: 0 fp32; 1 fp32+bias+res; 2 bf16 gelu(acc+bias); 3 fp32 partial at slice z;
//      4 self-QKV (rope Q,K -> Qro/Kro; V -> Vbo bf16)
template <int BM, int BN, int EPI, int DEPTH>
__global__ __launch_bounds__(256) void gemm3(const __bf16* __restrict__ A,
                                             const __bf16* __restrict__ BT,
                                             const float* __restrict__ bias,
                                             const float* __restrict__ res,
                                             void* __restrict__ outv,
                                             int M, int N, int K, int kslices,
                                             const float2* __restrict__ tbl,
                                             __bf16* __restrict__ Qro,
                                             __bf16* __restrict__ Kro,
                                             __bf16* __restrict__ Vbo,
                                             int Ntok) {
  constexpr int MI = BM / 32, NI = BN / 32;
  constexpr int NBUF = DEPTH + 1;
  constexpr int LPT = BM / 64 + BN / 64;
  __shared__ __bf16 sA[NBUF][BM * 32];
  __shared__ __bf16 sB[NBUF][BN * 32];
  const int t = threadIdx.x;
  const int w = t >> 6, lane = t & 63;
  const int lr = lane & 15, lg = lane >> 4;
  const int fxor = (lr >> 1) & 3;
  int nwg = gridDim.x * gridDim.y * gridDim.z;
  int flat = blockIdx.x + gridDim.x * (blockIdx.y + gridDim.y * blockIdx.z);
  flat = (flat & 7) * (nwg >> 3) + (flat >> 3);
  const int bm = flat % gridDim.x;
  int rest = flat / gridDim.x;
  const int bn = rest % gridDim.y;
  const int bz = rest / gridDim.y;
  const int wm = (w >> 1) * (BM / 2), wn = (w & 1) * (BN / 2);
  const int kper = K / kslices;
  const int k0 = bz * kper;
  const int nsteps = kper / 32;
  f32x4 acc[MI][NI] = {};

  auto stage = [&](int buf, int kt) {
#pragma unroll
    for (int i = 0; i < BM / 64; ++i) {
      int e8 = i * 256 + t;
      int row = e8 >> 2, c = e8 & 3;
      int scol = (c ^ ((row >> 1) & 3)) << 3;
      gload16(A + (size_t)(bm * BM + row) * K + kt + scol, &sA[buf][e8 * 8]);
    }
#pragma unroll
    for (int i = 0; i < BN / 64; ++i) {
      int e8 = i * 256 + t;
      int row = e8 >> 2, c = e8 & 3;
      int scol = (c ^ ((row >> 1) & 3)) << 3;
      gload16(BT + (size_t)(bn * BN + row) * K + kt + scol, &sB[buf][e8 * 8]);
    }
  };

  auto compute = [&](int buf) {
    bf16x8 af[MI], bfr[NI];
#pragma unroll
    for (int mi = 0; mi < MI; ++mi)
      af[mi] = *(const bf16x8*)(&sA[buf][(wm + mi * 16 + lr) * 32 + ((lg ^ fxor) << 3)]);
#pragma unroll
    for (int ni = 0; ni < NI; ++ni)
      bfr[ni] = *(const bf16x8*)(&sB[buf][(wn + ni * 16 + lr) * 32 + ((lg ^ fxor) << 3)]);
#pragma unroll
    for (int mi = 0; mi < MI; ++mi)
#pragma unroll
      for (int ni = 0; ni < NI; ++ni)
        acc[mi][ni] = __builtin_amdgcn_mfma_f32_16x16x32_bf16(af[mi], bfr[ni], acc[mi][ni], 0, 0, 0);
  };

#pragma unroll
  for (int i = 0; i < DEPTH; ++i) stage(i, k0 + i * 32);

  int it = 0;
  for (; it < nsteps - (DEPTH - 1); ++it) {
    asm volatile("s_waitcnt vmcnt(%0)" :: "n"((DEPTH - 1) * LPT) : "memory");
    __builtin_amdgcn_s_barrier();
    __builtin_amdgcn_sched_barrier(0);
    if (it + DEPTH < nsteps) stage((it + DEPTH) % NBUF, k0 + (it + DEPTH) * 32);
    compute(it % NBUF);
  }
  asm volatile("s_waitcnt vmcnt(0)" ::: "memory");
  __builtin_amdgcn_s_barrier();
  __builtin_amdgcn_sched_barrier(0);
  for (; it < nsteps; ++it) compute(it % NBUF);

#pragma unroll
  for (int mi = 0; mi < MI; ++mi) {
    int row = bm * BM + wm + mi * 16 + lg * 4;
#pragma unroll
    for (int ni = 0; ni < NI; ++ni) {
      int col = bn * BN + wn + ni * 16 + lr;
#pragma unroll
      for (int r = 0; r < 4; ++r) {
        float v = acc[mi][ni][r];
        int erow = row + r;
        size_t off = (size_t)erow * N + col;
        if (EPI == 0) {
          ((float*)outv)[off] = v;
        } else if (EPI == 1) {
          ((float*)outv)[off] = v + bias[col] + res[off];
        } else if (EPI == 2) {
          ((__bf16*)outv)[off] = (__bf16)fast_gelu(v + bias[col]);
        } else if (EPI == 3) {
          ((float*)outv)[(size_t)bz * M * N + off] = v;
        } else if (EPI == 4) {
          float ov = __shfl_xor(v, 1);
          int b = erow >> 10, n = erow & 1023;
          if (col < 2048) {
            int h = (col >> 6) & 15, dh = col & 63;
            float2 sc = tbl[n * 32 + (dh >> 1)];
            float rv = (lr & 1) ? (ov * sc.x + v * sc.y) : (v * sc.y - ov * sc.x);
            __bf16* dst;
            if (col < 1024) { rv *= 0.125f; dst = Qro; } else dst = Kro;
            dst[((size_t)(b * 16 + h) * Ntok + n) * 64 + dh] = (__bf16)rv;
          } else {
            Vbo[(size_t)erow * 1024 + (col - 2048)] = (__bf16)v;
          }
        }
      }
    }
  }
}

// ---------------- BK=64 GEMM: 128x64 tile, one vmcnt+barrier per 64-wide K-step ----------------
// Only for grids <= 512 (or exact multiples of 512): 72KB LDS -> 2 blocks/CU.
// EPI: 2 bf16 gelu(acc+bias); 3 fp32 partial at slice z
template <int EPI, int DEPTH>
__global__ __launch_bounds__(256) void gemm64(const __bf16* __restrict__ A,
                                              const __bf16* __restrict__ BT,
                                              const float* __restrict__ bias,
                                              const float* __restrict__ res,
                                              void* __restrict__ outv,
                                              int M, int N, int K, int kslices,
                                              const float2* __restrict__ tbl,
                                              __bf16* __restrict__ Qro,
                                              __bf16* __restrict__ Kro,
                                              __bf16* __restrict__ Vbo,
                                              int Ntok) {
  constexpr int BM = 128, BN = 64;
  constexpr int NBUF = DEPTH + 1;
  constexpr int LPT = 6;  // 4 A + 2 B gload16 per thread per stage
  __shared__ __bf16 sA[NBUF][BM * 64];
  __shared__ __bf16 sB[NBUF][BN * 64];
  const int t = threadIdx.x;
  const int w = t >> 6, lane = t & 63;
  const int lr = lane & 15, lg = lane >> 4;
  const int sx = lr & 7;
  int nwg = gridDim.x * gridDim.y * gridDim.z;
  int flat = blockIdx.x + gridDim.x * (blockIdx.y + gridDim.y * blockIdx.z);
  flat = (flat & 7) * (nwg >> 3) + (flat >> 3);
  const int bm = flat % gridDim.x;
  int rest = flat / gridDim.x;
  const int bn = rest % gridDim.y;
  const int bz = rest / gridDim.y;
  const int wm = (w >> 1) * 64, wn = (w & 1) * 32;
  const int kper = K / kslices;
  const int k0 = bz * kper;
  const int nsteps = kper / 64;
  f32x4 acc[4][2] = {};

  auto stage = [&](int buf, int kt) {
#pragma unroll
    for (int i = 0; i < 4; ++i) {
      int e8 = i * 256 + t;
      int row = e8 >> 3, c = e8 & 7;
      int scol = (c ^ (row & 7)) << 3;
      gload16(A + (size_t)(bm * BM + row) * K + kt + scol, &sA[buf][e8 * 8]);
    }
#pragma unroll
    for (int i = 0; i < 2; ++i) {
      int e8 = i * 256 + t;
      int row = e8 >> 3, c = e8 & 7;
      int scol = (c ^ (row & 7)) << 3;
      gload16(BT + (size_t)(bn * BN + row) * K + kt + scol, &sB[buf][e8 * 8]);
    }
  };

  auto compute = [&](int buf) {
#pragma unroll
    for (int kk = 0; kk < 2; ++kk) {
      bf16x8 af[4], bfr[2];
#pragma unroll
      for (int mi = 0; mi < 4; ++mi)
        af[mi] = *(const bf16x8*)(&sA[buf][(wm + mi * 16 + lr) * 64 + (((kk * 4 + lg) ^ sx) << 3)]);
#pragma unroll
      for (int ni = 0; ni < 2; ++ni)
        bfr[ni] = *(const bf16x8*)(&sB[buf][(wn + ni * 16 + lr) * 64 + (((kk * 4 + lg) ^ sx) << 3)]);
#pragma unroll
      for (int mi = 0; mi < 4; ++mi)
#pragma unroll
        for (int ni = 0; ni < 2; ++ni)
          acc[mi][ni] = __builtin_amdgcn_mfma_f32_16x16x32_bf16(af[mi], bfr[ni], acc[mi][ni], 0, 0, 0);
    }
  };

#pragma unroll
  for (int i = 0; i < DEPTH; ++i) stage(i, k0 + i * 64);

  int it = 0;
  for (; it < nsteps - (DEPTH - 1); ++it) {
    asm volatile("s_waitcnt vmcnt(%0)" :: "n"((DEPTH - 1) * LPT) : "memory");
    __builtin_amdgcn_s_barrier();
    __builtin_amdgcn_sched_barrier(0);
    if (it + DEPTH < nsteps) stage((it + DEPTH) % NBUF, k0 + (it + DEPTH) * 64);
    compute(it % NBUF);
  }
  asm volatile("s_waitcnt vmcnt(0)" ::: "memory");
  __builtin_amdgcn_s_barrier();
  __builtin_amdgcn_sched_barrier(0);
  for (; it < nsteps; ++it) compute(it % NBUF);

#pragma unroll
  for (int mi = 0; mi < 4; ++mi) {
    int row = bm * BM + wm + mi * 16 + lg * 4;
#pragma unroll
    for (int ni = 0; ni < 2; ++ni) {
      int col = bn * BN + wn + ni * 16 + lr;
#pragma unroll
      for (int r = 0; r < 4; ++r) {
        float v = acc[mi][ni][r];
        size_t off = (size_t)(row + r) * N + col;
        if (EPI == 2) {
          ((__bf16*)outv)[off] = (__bf16)fast_gelu(v + bias[col]);
        } else if (EPI == 3) {
          ((float*)outv)[(size_t)bz * M * N + off] = v;
        }
      }
    }
  }
}

// ---------------- fused cross-attn projections, BK=64: 512 blocks = cq (256) + ckv (256) ------
__global__ __launch_bounds__(256) void gemm_cross(const __bf16* __restrict__ Aq,
                                                  const __bf16* __restrict__ Bq,
                                                  const __bf16* __restrict__ Akv,
                                                  const __bf16* __restrict__ Bkv,
                                                  const float2* __restrict__ tbl,
                                                  __bf16* __restrict__ Qro,
                                                  __bf16* __restrict__ Kro,
                                                  __bf16* __restrict__ Vbo) {
  constexpr int BM = 128, BN = 64, DEPTH = 2, NBUF = 3, LPT = 6;
  __shared__ __bf16 sA[NBUF][BM * 64];
  __shared__ __bf16 sB[NBUF][BN * 64];
  const int t = threadIdx.x;
  const int w = t >> 6, lane = t & 63;
  const int lr = lane & 15, lg = lane >> 4;
  const int sx = lr & 7;
  int flat = blockIdx.x;
  flat = (flat & 7) * 64 + (flat >> 3);  // bijective XCD swizzle over 512
  const bool isq = flat < 256;
  const __bf16* A  = isq ? Aq : Akv;
  const __bf16* BT = isq ? Bq : Bkv;
  const int K = isq ? 1024 : 768;
  int lf = isq ? flat : flat - 256;
  const int bm = isq ? (lf & 15) : (lf & 7);
  const int bn = isq ? (lf >> 4) : (lf >> 3);
  const int wm = (w >> 1) * 64, wn = (w & 1) * 32;
  const int nsteps = K >> 6;  // 16 or 12
  f32x4 acc[4][2] = {};

  auto stage = [&](int buf, int kt) {
#pragma unroll
    for (int i = 0; i < 4; ++i) {
      int e8 = i * 256 + t;
      int row = e8 >> 3, c = e8 & 7;
      int scol = (c ^ (row & 7)) << 3;
      gload16(A + (size_t)(bm * BM + row) * K + kt + scol, &sA[buf][e8 * 8]);
    }
#pragma unroll
    for (int i = 0; i < 2; ++i) {
      int e8 = i * 256 + t;
      int row = e8 >> 3, c = e8 & 7;
      int scol = (c ^ (row & 7)) << 3;
      gload16(BT + (size_t)(bn * BN + row) * K + kt + scol, &sB[buf][e8 * 8]);
    }
  };

  auto compute = [&](int buf) {
#pragma unroll
    for (int kk = 0; kk < 2; ++kk) {
      bf16x8 af[4], bfr[2];
#pragma unroll
      for (int mi = 0; mi < 4; ++mi)
        af[mi] = *(const bf16x8*)(&sA[buf][(wm + mi * 16 + lr) * 64 + (((kk * 4 + lg) ^ sx) << 3)]);
#pragma unroll
      for (int ni = 0; ni < 2; ++ni)
        bfr[ni] = *(const bf16x8*)(&sB[buf][(wn + ni * 16 + lr) * 64 + (((kk * 4 + lg) ^ sx) << 3)]);
#pragma unroll
      for (int mi = 0; mi < 4; ++mi)
#pragma unroll
        for (int ni = 0; ni < 2; ++ni)
          acc[mi][ni] = __builtin_amdgcn_mfma_f32_16x16x32_bf16(af[mi], bfr[ni], acc[mi][ni], 0, 0, 0);
    }
  };

#pragma unroll
  for (int i = 0; i < DEPTH; ++i) stage(i, i * 64);

  int it = 0;
  for (; it < nsteps - (DEPTH - 1); ++it) {
    asm volatile("s_waitcnt vmcnt(%0)" :: "n"((DEPTH - 1) * LPT) : "memory");
    __builtin_amdgcn_s_barrier();
    __builtin_amdgcn_sched_barrier(0);
    if (it + DEPTH < nsteps) stage((it + DEPTH) % NBUF, (it + DEPTH) * 64);
    compute(it % NBUF);
  }
  asm volatile("s_waitcnt vmcnt(0)" ::: "memory");
  __builtin_amdgcn_s_barrier();
  __builtin_amdgcn_sched_barrier(0);
  for (; it < nsteps; ++it) compute(it % NBUF);

#pragma unroll
  for (int mi = 0; mi < 4; ++mi) {
    int row = bm * 128 + wm + mi * 16 + lg * 4;
#pragma unroll
    for (int ni = 0; ni < 2; ++ni) {
      int col = bn * 64 + wn + ni * 16 + lr;
#pragma unroll
      for (int r = 0; r < 4; ++r) {
        float v = acc[mi][ni][r];
        int erow = row + r;
        float ov = __shfl_xor(v, 1);
        if (isq) {
          int b = erow >> 10, n = erow & 1023;
          int h = col >> 6, dh = col & 63;
          float2 sc = tbl[n * 32 + (dh >> 1)];
          float rv = ((lr & 1) ? (ov * sc.x + v * sc.y) : (v * sc.y - ov * sc.x)) * 0.125f;
          Qro[((size_t)(b * 16 + h) * 1024 + n) * 64 + dh] = (__bf16)rv;
        } else {
          int b = erow >> 9, n = erow & 511;
          if (col < 1024) {
            int h = col >> 6, dh = col & 63;
            float2 sc = tbl[n * 32 + (dh >> 1)];
            float rv = (lr & 1) ? (ov * sc.x + v * sc.y) : (v * sc.y - ov * sc.x);
            Kro[((size_t)(b * 16 + h) * 512 + n) * 64 + dh] = (__bf16)rv;
          } else {
            Vbo[(size_t)erow * 1024 + (col - 1024)] = (__bf16)v;
          }
        }
      }
    }
  }
}

// ---------------- split-K reduce: out = p0+p1+bias+res (final ff2 only) ----------------
__global__ __launch_bounds__(256) void ff2red_kernel(const float* __restrict__ part,
                                                     const float* __restrict__ bias,
                                                     const float* __restrict__ res,
                                                     float* __restrict__ out, int MN, int N) {
  int idx = blockIdx.x * 256 + threadIdx.x;
  float4 p0 = ((const float4*)part)[idx];
  float4 p1 = ((const float4*)(part + MN))[idx];
  float4 rr = ((const float4*)res)[idx];
  int colb = (idx * 4) & (N - 1);
  float4 bb = *(const float4*)(bias + colb);
  float4 o;
  o.x = p0.x + p1.x + bb.x + rr.x;
  o.y = p0.y + p1.y + bb.y + rr.y;
  o.z = p0.z + p1.z + bb.z + rr.z;
  o.w = p0.w + p1.w + bb.w + rr.w;
  ((float4*)out)[idx] = o;
}

// ---------------- attention, LDS-staged K/V, direct normalized bf16 output ----------------
template <int KITERS>
__global__ __launch_bounds__(256) void attn_kernel(const __bf16* __restrict__ Qr,
                                                   const __bf16* __restrict__ Kr,
                                                   const __bf16* __restrict__ VT,
                                                   __bf16* __restrict__ O,
                                                   int Nq, int Nk) {
  __shared__ __bf16 sK[2][64 * 64];
  __shared__ __bf16 sV[2][64 * 64];
  __shared__ __bf16 Pl[4][16 * 64];
  const int t = threadIdx.x, w = t >> 6, lane = t & 63;
  const int lr = lane & 15, lg = lane >> 4;
  const int lsrc = lane & 48;
  const int swz = (lr & 7) << 3;
  int flat = blockIdx.x + (blockIdx.y << 4);  // grid 16x32
  flat = (flat & 7) * 64 + (flat >> 3);
  const int bh = flat >> 4;
  const int q0 = (flat & 15) * 64 + w * 16;
  const int b = bh >> 4, h = bh & 15;

  auto stage = [&](int buf, int kt) {
#pragma unroll
    for (int i = 0; i < 2; ++i) {
      int e8 = i * 256 + t;
      int row = e8 >> 3, col8 = e8 & 7;
      int scol = (col8 ^ (row & 7)) << 3;
      gload16(Kr + ((size_t)bh * Nk + kt + row) * 64 + scol, &sK[buf][e8 * 8]);
      gload16(VT + ((size_t)bh * 64 + row) * Nk + kt + scol, &sV[buf][e8 * 8]);
    }
  };

  bf16x8 qf[2];
#pragma unroll
  for (int kh = 0; kh < 2; ++kh)
    qf[kh] = *(const bf16x8*)(Qr + ((size_t)bh * Nq + q0 + lr) * 64 + kh * 32 + lg * 8);
  f32x4 accO[4] = {};
  float m = -INFINITY, l = 0.f;

  stage(0, 0);
  __syncthreads();
  int cur = 0;
#pragma unroll
  for (int it = 0; it < KITERS; ++it) {
    if (it + 1 < KITERS) stage(cur ^ 1, (it + 1) * 64);
    f32x4 s[4] = {};
#pragma unroll
    for (int nf = 0; nf < 4; ++nf) {
      int r = nf * 16 + lr;
#pragma unroll
      for (int kh = 0; kh < 2; ++kh) {
        bf16x8 kf = *(const bf16x8*)(&sK[cur][r * 64 + (((kh * 4 + lg) ^ (lr & 7)) << 3)]);
        s[nf] = __builtin_amdgcn_mfma_f32_16x16x32_bf16(kf, qf[kh], s[nf], 0, 0, 0);
      }
    }
    float p[16];
#pragma unroll
    for (int j = 0; j < 16; ++j) p[j] = s[j >> 2][j & 3];
    float pm = p[0];
#pragma unroll
    for (int j = 1; j < 16; ++j) pm = fmaxf(pm, p[j]);
    pm = fmaxf(pm, __shfl_xor(pm, 16));
    pm = fmaxf(pm, __shfl_xor(pm, 32));
    if (!__all(pm <= m + 8.f)) {  // defer-max
      float mnew = fmaxf(m, pm);
      float resc = __expf(m - mnew);
      float rq[4];
#pragma unroll
      for (int r = 0; r < 4; ++r) rq[r] = __shfl(resc, lsrc | (lg * 4 + r));
#pragma unroll
      for (int df = 0; df < 4; ++df)
#pragma unroll
        for (int r = 0; r < 4; ++r) accO[df][r] *= rq[r];
      l *= resc;
      m = mnew;
    }
    float rs = 0.f;
#pragma unroll
    for (int j = 0; j < 16; ++j) { p[j] = __expf(p[j] - m); rs += p[j]; }
    rs += __shfl_xor(rs, 16);
    rs += __shfl_xor(rs, 32);
    l += rs;
#pragma unroll
    for (int nf = 0; nf < 4; ++nf)
#pragma unroll
      for (int jj = 0; jj < 2; ++jj) {
        int k = nf * 16 + lg * 4 + 2 * jj;
        bf16x2 pk;
        pk[0] = (__bf16)p[nf * 4 + 2 * jj];
        pk[1] = (__bf16)p[nf * 4 + 2 * jj + 1];
        *(bf16x2*)(&Pl[w][lr * 64 + (k ^ swz)]) = pk;
      }
    bf16x8 pa0 = *(const bf16x8*)(&Pl[w][lr * 64 + ((lg * 8) ^ swz)]);
    bf16x8 pa1 = *(const bf16x8*)(&Pl[w][lr * 64 + ((32 + lg * 8) ^ swz)]);
#pragma unroll
    for (int df = 0; df < 4; ++df) {
      int d = df * 16 + lr;
      bf16x8 vf0 = *(const bf16x8*)(&sV[cur][d * 64 + ((lg ^ (lr & 7)) << 3)]);
      bf16x8 vf1 = *(const bf16x8*)(&sV[cur][d * 64 + (((4 + lg) ^ (lr & 7)) << 3)]);
      accO[df] = __builtin_amdgcn_mfma_f32_16x16x32_bf16(pa0, vf0, accO[df], 0, 0, 0);
      accO[df] = __builtin_amdgcn_mfma_f32_16x16x32_bf16(pa1, vf1, accO[df], 0, 0, 0);
    }
    __syncthreads();
    cur ^= 1;
  }
  float lq[4];
#pragma unroll
  for (int r = 0; r < 4; ++r) lq[r] = __shfl(l, lsrc | (lg * 4 + r));
#pragma unroll
  for (int r = 0; r < 4; ++r) {
    float inv = 1.0f / lq[r];
    int n = q0 + lg * 4 + r;
#pragma unroll
    for (int df = 0; df < 4; ++df)
      O[(size_t)(b * 1024 + n) * 1024 + h * 64 + df * 16 + lr] = (__bf16)(accO[df][r] * inv);
  }
}

extern "C" void kernel_launch(void* const* d_in, const int* in_sizes, int n_in,
                              void* d_out, int out_size, void* d_ws, size_t ws_size,
                              hipStream_t stream) {
  (void)in_sizes; (void)n_in; (void)out_size; (void)ws_size;
  const float* x       = (const float*)d_in[0];
  const float* cond    = (const float*)d_in[1];
  const float* ctx     = (const float*)d_in[2];
  const float* ln1_w   = (const float*)d_in[3];
  const float* ln1_b   = (const float*)d_in[4];
  const float* g1_w    = (const float*)d_in[5];
  const float* g1_b    = (const float*)d_in[6];
  const float* b1_w    = (const float*)d_in[7];
  const float* b1_b    = (const float*)d_in[8];
  const float* ln2_w   = (const float*)d_in[9];
  const float* ln2_b   = (const float*)d_in[10];
  const float* g2_w    = (const float*)d_in[11];
  const float* g2_b    = (const float*)d_in[12];
  const float* b2_w    = (const float*)d_in[13];
  const float* b2_b    = (const float*)d_in[14];
  const float* sa_wq   = (const float*)d_in[15];
  const float* sa_wkv  = (const float*)d_in[16];
  const float* sa_wo   = (const float*)d_in[17];
  const float* sa_bo   = (const float*)d_in[18];
  const float* ca_lnc_w = (const float*)d_in[19];
  const float* ca_lnc_b = (const float*)d_in[20];
  const float* ca_wq   = (const float*)d_in[21];
  const float* ca_wkv  = (const float*)d_in[22];
  const float* ca_wo   = (const float*)d_in[23];
  const float* ca_bo   = (const float*)d_in[24];
  const float* ff_w1   = (const float*)d_in[25];
  const float* ff_b1   = (const float*)d_in[26];
  const float* ff_w2   = (const float*)d_in[27];
  const float* ff_b2   = (const float*)d_in[28];
  float* out = (float*)d_out;

  char* ws = (char*)d_ws;
  size_t o = 0;
  auto alloc = [&](size_t bytes) {
    void* p = ws + o;
    o += (bytes + 255) & ~(size_t)255;
    return p;
  };

  __bf16* wqT   = (__bf16*)alloc(1024ull * 1024 * 2);  // wqT+wkvT contiguous => BT[3072][1024]
  __bf16* wkvT  = (__bf16*)alloc(2048ull * 1024 * 2);
  __bf16* woT   = (__bf16*)alloc(1024ull * 1024 * 2);
  __bf16* cwqT  = (__bf16*)alloc(1024ull * 1024 * 2);
  __bf16* cwkvT = (__bf16*)alloc(2048ull * 768 * 2);
  __bf16* cwoT  = (__bf16*)alloc(1024ull * 1024 * 2);
  __bf16* ff1T  = (__bf16*)alloc(4096ull * 1024 * 2);
  __bf16* ff2T  = (__bf16*)alloc(1024ull * 4096 * 2);
  float*  mods  = (float*)alloc(4ull * 2 * 1024 * 4);
  float2* tbl   = (float2*)alloc(1024ull * 32 * 8);
  __bf16* ain   = (__bf16*)alloc(2048ull * 1024 * 2);
  float*  Qf    = (float*)alloc(2048ull * 1024 * 4);
  float*  KVf   = (float*)alloc(2048ull * 2048 * 4);
  __bf16* ctxn  = (__bf16*)alloc(1024ull * 768 * 2);
  __bf16* Qr    = (__bf16*)alloc(2048ull * 1024 * 2);
  __bf16* Kr    = (__bf16*)alloc(2048ull * 1024 * 2);
  __bf16* VTb   = (__bf16*)alloc(2048ull * 1024 * 2);
  __bf16* Ob    = (__bf16*)alloc(2048ull * 1024 * 2);
  float*  x1    = (float*)alloc(2048ull * 1024 * 4);
  float*  x2    = (float*)alloc(2048ull * 1024 * 4);
  __bf16* hb    = (__bf16*)KVf;   // FFN hidden (2048x4096 bf16)
  float*  pbuf  = (float*)Qr;     // ff2 split-K partials: 2 x 8MB (Qr..Ob dead in FFN)
  float*  wopb  = (float*)KVf;    // wo split-K partials: 2 x 8MB (KVf free during attn phases)
  float*  mpart = (float*)Qf;     // mod GEMV partials (dead after mod_reduce)
  __bf16* Vb    = (__bf16*)Qf;    // V bf16 token-major (written by QKV/ckv epilogues)

  // ---- fused prep (vectorized 32x128 transposes) ----
  WtDesc wd;
  const float* srcs[8] = {sa_wq, sa_wkv, sa_wo, ca_wq, ca_wkv, ca_wo, ff_w1, ff_w2};
  __bf16* dsts[8] = {wqT, wkvT, woT, cwqT, cwkvT, cwoT, ff1T, ff2T};
  int Ks[8] = {1024, 1024, 1024, 1024, 768, 1024, 1024, 4096};
  int Ns[8] = {1024, 2048, 1024, 1024, 2048, 1024, 4096, 1024};
  int cum = 0;
  for (int i = 0; i < 8; ++i) {
    wd.src[i] = srcs[i]; wd.dst[i] = dsts[i]; wd.K[i] = Ks[i]; wd.N[i] = Ns[i];
    wd.tstart[i] = cum;
    cum += (Ks[i] >> 5) * (Ns[i] >> 7);
  }
  wd.tstart[8] = cum;  // 3968
  prep_kernel<<<cum + 128 + 256, 256, 0, stream>>>(wd, tbl, cond, g1_w, b1_w, g2_w, b2_w, mpart);
  mod_reduce_kernel<<<32, 256, 0, stream>>>(mpart, g1_b, b1_b, g2_b, b2_b, mods);

  // ---- self attention ----
  adaln_kernel<<<2048, 256, 0, stream>>>(x, ln1_w, ln1_b, mods, 0, 1, ain);
  gemm3<128, 64, 4, 3><<<dim3(16, 48), 256, 0, stream>>>(ain, wqT, nullptr, nullptr, nullptr,
                                                         2048, 3072, 1024, 1, tbl, Qr, Kr, Vb, 1024);
  vtb_kernel<<<dim3(32, 16), 256, 0, stream>>>(Vb, VTb, 1024);
  attn_kernel<16><<<dim3(16, 32), 256, 0, stream>>>(Qr, Kr, VTb, Ob, 1024, 1024);
  gemm64<3, 2><<<dim3(16, 16, 2), 256, 0, stream>>>(Ob, woT, nullptr, nullptr, wopb,
                                                    2048, 1024, 1024, 2, nullptr, nullptr, nullptr, nullptr, 0);
  red_adaln_kernel<<<2048, 256, 0, stream>>>(wopb, sa_bo, x, ln1_w, ln1_b, mods, 0, 1,
                                             2048 * 1024, x1, ain);

  // ---- cross attention ----
  ctxln_kernel<<<1024, 256, 0, stream>>>(ctx, ca_lnc_w, ca_lnc_b, ctxn);
  gemm_cross<<<512, 256, 0, stream>>>(ain, cwqT, ctxn, cwkvT, tbl, Qr, Kr, Vb);
  vtb_kernel<<<dim3(32, 8), 256, 0, stream>>>(Vb, VTb, 512);
  attn_kernel<8><<<dim3(16, 32), 256, 0, stream>>>(Qr, Kr, VTb, Ob, 1024, 512);
  gemm64<3, 2><<<dim3(16, 16, 2), 256, 0, stream>>>(Ob, cwoT, nullptr, nullptr, wopb,
                                                    2048, 1024, 1024, 2, nullptr, nullptr, nullptr, nullptr, 0);
  red_adaln_kernel<<<2048, 256, 0, stream>>>(wopb, ca_bo, x1, ln2_w, ln2_b, mods, 2, 3,
                                             2048 * 1024, x2, ain);

  // ---- FFN ----
  gemm64<2, 2><<<dim3(16, 64), 256, 0, stream>>>(ain, ff1T, ff_b1, nullptr, hb,
                                                 2048, 4096, 1024, 1, nullptr, nullptr, nullptr, nullptr, 0);
  gemm64<3, 2><<<dim3(16, 16, 2), 256, 0, stream>>>(hb, ff2T, nullptr, nullptr, pbuf,
                                                    2048, 1024, 4096, 2, nullptr, nullptr, nullptr, nullptr, 0);
  ff2red_kernel<<<2048, 256, 0, stream>>>(pbuf, ff_b2, x2, out, 2048 * 1024, 1024);
}

// Round 22
// 234.396 us; speedup vs baseline: 1.0825x; 1.0115x over previous
//
#include <hip/hip_runtime.h>
#include <hip/hip_bf16.h>
#include <math.h>

// B=2 N=1024 M=512 D=1024 H=16 DH=64 MID=1024 DC=768 MULT=4
// Converged config (= round 19, best measured 235.3 us):
//   QKV: gemm3<128,64,EPI4,D3> (768 blk, 3/CU, BK=32)
//   wo x2 / ff2: gemm64<D2> (512 blk, 2/CU, BK=64, partial-store epilogue)
//   ff1: gemm3<128,128,EPI2,D2> (512 blk, dense tile)
//   cross: gemm_cross BK=32 D3 (512 blk)

typedef float f32x4 __attribute__((ext_vector_type(4)));
typedef __bf16 bf16x8 __attribute__((ext_vector_type(8)));
typedef __bf16 bf16x4 __attribute__((ext_vector_type(4)));
typedef __bf16 bf16x2 __attribute__((ext_vector_type(2)));

#define DEVI __device__ __forceinline__

DEVI void gload16(const void* g, void* l) {
  __builtin_amdgcn_global_load_lds((const __attribute__((address_space(1))) void*)g,
                                   (__attribute__((address_space(3))) void*)l, 16, 0, 0);
}

// exact-GELU via A&S 7.1.26 erf poly (|err|<=1.5e-7, far below bf16 noise)
DEVI float fast_gelu(float x) {
  float a = fabsf(x) * 0.7071067811865475f;
  float tt = 1.0f / (1.0f + 0.3275911f * a);
  float p = tt * (0.254829592f + tt * (-0.284496736f + tt * (1.421413741f +
            tt * (-1.453152027f + tt * 1.061405429f))));
  float er = 1.0f - p * __expf(-a * a);
  er = (x < 0.f) ? -er : er;
  return 0.5f * x * (1.0f + er);
}

// ---------------- fused prep: vectorized transposes (32k x 128n tiles) + rope tbl + mod partials ----
struct WtDesc {
  const float* src[8];
  __bf16* dst[8];
  int K[8], N[8];
  int tstart[9];
};

__global__ __launch_bounds__(256) void prep_kernel(WtDesc d,
                                                   float2* __restrict__ tbl,
                                                   const float* __restrict__ cond,
                                                   const float* __restrict__ g1w,
                                                   const float* __restrict__ b1w,
                                                   const float* __restrict__ g2w,
                                                   const float* __restrict__ b2w,
                                                   float* __restrict__ part) {
  __shared__ float smem[32 * 129];
  int blk = blockIdx.x;
  int wtend = d.tstart[8];
  int t = threadIdx.x;
  if (blk < wtend) {
    int e = 0;
#pragma unroll
    for (int i = 0; i < 7; ++i) e += (blk >= d.tstart[i + 1]) ? 1 : 0;
    int li = blk - d.tstart[e];
    const float* W = d.src[e];
    __bf16* WT = d.dst[e];
    int K = d.K[e], N = d.N[e];
    int ntx = N >> 7;
    int n0 = (li % ntx) * 128, k0 = (li / ntx) * 32;
    int tx = t & 31, ty = t >> 5;
#pragma unroll
    for (int i = 0; i < 4; ++i) {
      int k = ty + i * 8;
      f32x4 v = *(const f32x4*)(W + (size_t)(k0 + k) * N + n0 + tx * 4);
#pragma unroll
      for (int j = 0; j < 4; ++j) smem[k * 129 + tx * 4 + j] = v[j];
    }
    __syncthreads();
    int kc = t & 3;
#pragma unroll
    for (int i = 0; i < 2; ++i) {
      int n = i * 64 + (t >> 2);
      bf16x8 o;
#pragma unroll
      for (int j = 0; j < 8; ++j) o[j] = (__bf16)smem[(kc * 8 + j) * 129 + n];
      *(bf16x8*)(WT + (size_t)(n0 + n) * K + k0 + kc * 8) = o;
    }
  } else if (blk < wtend + 128) {
    int idx = (blk - wtend) * 256 + t;
    int n = idx >> 5, i = idx & 31;
    float inv = expf(-(float)(2 * i) * (1.0f / 64.0f) * 9.210340371976184f);
    float ang = (float)n * inv;
    tbl[idx] = make_float2(sinf(ang), cosf(ang));
  } else {
    int f = blk - wtend - 128;
    int dchunk = f & 3, b = (f >> 2) & 1, z = f >> 3;
    int mat = z >> 3, ks = z & 7;
    const float* W = (mat == 0) ? g1w : (mat == 1) ? b1w : (mat == 2) ? g2w : b2w;
    float* sc = smem;
    if (t < 128) sc[t] = cond[b * 1024 + ks * 128 + t];
    __syncthreads();
    int dd = dchunk * 256 + t;
    const float* Wp = W + (size_t)(ks * 128) * 1024 + dd;
    float acc = 0.f;
#pragma unroll 8
    for (int k = 0; k < 128; ++k) acc += sc[k] * Wp[(size_t)k * 1024];
    part[(size_t)(z * 2 + b) * 1024 + dd] = acc;
  }
}

__global__ __launch_bounds__(256) void mod_reduce_kernel(
    const float* __restrict__ part,
    const float* __restrict__ g1b, const float* __restrict__ b1b,
    const float* __restrict__ g2b, const float* __restrict__ b2b,
    float* __restrict__ mods) {
  int idx = blockIdx.x * 256 + threadIdx.x;
  int mat = idx >> 11, b = (idx >> 10) & 1, d = idx & 1023;
  float s = 0.f;
#pragma unroll
  for (int ks = 0; ks < 8; ++ks) s += part[(size_t)((mat * 8 + ks) * 2 + b) * 1024 + d];
  const float* Bv = (mat == 0) ? g1b : (mat == 1) ? b1b : (mat == 2) ? g2b : b2b;
  mods[(size_t)(mat * 2 + b) * 1024 + d] = s + Bv[d];
}

// ---------------- adaLN (first block only) ----------------
__global__ __launch_bounds__(256) void adaln_kernel(const float* __restrict__ X,
                                                    const float* __restrict__ lnw,
                                                    const float* __restrict__ lnb,
                                                    const float* __restrict__ mods,
                                                    int gi, int bi,
                                                    __bf16* __restrict__ out) {
  __shared__ float red[2][4];
  int row = blockIdx.x;
  int b = row >> 10;
  int t = threadIdx.x;
  const float4 xv = ((const float4*)(X + (size_t)row * 1024))[t];
  float s  = xv.x + xv.y + xv.z + xv.w;
  float s2 = xv.x * xv.x + xv.y * xv.y + xv.z * xv.z + xv.w * xv.w;
  int lane = t & 63, w = t >> 6;
#pragma unroll
  for (int off = 32; off > 0; off >>= 1) {
    s += __shfl_down(s, off);
    s2 += __shfl_down(s2, off);
  }
  if (lane == 0) { red[0][w] = s; red[1][w] = s2; }
  __syncthreads();
  s  = red[0][0] + red[0][1] + red[0][2] + red[0][3];
  s2 = red[1][0] + red[1][1] + red[1][2] + red[1][3];
  float mu = s * (1.0f / 1024.0f);
  float var = s2 * (1.0f / 1024.0f) - mu * mu;
  float rstd = rsqrtf(var + 1e-5f);
  const float4 wv = ((const float4*)lnw)[t];
  const float4 bv = ((const float4*)lnb)[t];
  const float4 gv = ((const float4*)(mods + (size_t)(gi * 2 + b) * 1024))[t];
  const float4 tv = ((const float4*)(mods + (size_t)(bi * 2 + b) * 1024))[t];
  bf16x4 ov;
  ov[0] = (__bf16)(((xv.x - mu) * rstd * wv.x + bv.x) * (1.0f + gv.x) + tv.x);
  ov[1] = (__bf16)(((xv.y - mu) * rstd * wv.y + bv.y) * (1.0f + gv.y) + tv.y);
  ov[2] = (__bf16)(((xv.z - mu) * rstd * wv.z + bv.z) * (1.0f + gv.z) + tv.z);
  ov[3] = (__bf16)(((xv.w - mu) * rstd * wv.w + bv.w) * (1.0f + gv.w) + tv.w);
  *(bf16x4*)(out + (size_t)row * 1024 + t * 4) = ov;
}

// ---------------- fused split-K reduce + bias + residual + adaLN ----------------
__global__ __launch_bounds__(256) void red_adaln_kernel(const float* __restrict__ part,
                                                        const float* __restrict__ bias,
                                                        const float* __restrict__ res,
                                                        const float* __restrict__ lnw,
                                                        const float* __restrict__ lnb,
                                                        const float* __restrict__ mods,
                                                        int gi, int bi, int MN,
                                                        float* __restrict__ xout,
                                                        __bf16* __restrict__ ain) {
  __shared__ float red[2][4];
  int row = blockIdx.x;
  int b = row >> 10;
  int t = threadIdx.x;
  size_t base = (size_t)row * 1024 + t * 4;
  float4 p0 = *(const float4*)(part + base);
  float4 p1 = *(const float4*)(part + MN + base);
  float4 rr = *(const float4*)(res + base);
  float4 bb = ((const float4*)bias)[t];
  float4 y;
  y.x = p0.x + p1.x + bb.x + rr.x;
  y.y = p0.y + p1.y + bb.y + rr.y;
  y.z = p0.z + p1.z + bb.z + rr.z;
  y.w = p0.w + p1.w + bb.w + rr.w;
  *(float4*)(xout + base) = y;
  float s  = y.x + y.y + y.z + y.w;
  float s2 = y.x * y.x + y.y * y.y + y.z * y.z + y.w * y.w;
  int lane = t & 63, w = t >> 6;
#pragma unroll
  for (int off = 32; off > 0; off >>= 1) {
    s += __shfl_down(s, off);
    s2 += __shfl_down(s2, off);
  }
  if (lane == 0) { red[0][w] = s; red[1][w] = s2; }
  __syncthreads();
  s  = red[0][0] + red[0][1] + red[0][2] + red[0][3];
  s2 = red[1][0] + red[1][1] + red[1][2] + red[1][3];
  float mu = s * (1.0f / 1024.0f);
  float var = s2 * (1.0f / 1024.0f) - mu * mu;
  float rstd = rsqrtf(var + 1e-5f);
  const float4 wv = ((const float4*)lnw)[t];
  const float4 bv = ((const float4*)lnb)[t];
  const float4 gv = ((const float4*)(mods + (size_t)(gi * 2 + b) * 1024))[t];
  const float4 tv = ((const float4*)(mods + (size_t)(bi * 2 + b) * 1024))[t];
  bf16x4 ov;
  ov[0] = (__bf16)(((y.x - mu) * rstd * wv.x + bv.x) * (1.0f + gv.x) + tv.x);
  ov[1] = (__bf16)(((y.y - mu) * rstd * wv.y + bv.y) * (1.0f + gv.y) + tv.y);
  ov[2] = (__bf16)(((y.z - mu) * rstd * wv.z + bv.z) * (1.0f + gv.z) + tv.z);
  ov[3] = (__bf16)(((y.w - mu) * rstd * wv.w + bv.w) * (1.0f + gv.w) + tv.w);
  *(bf16x4*)(ain + (size_t)row * 1024 + t * 4) = ov;
}

// ---------------- context LN (D=768) ----------------
__global__ __launch_bounds__(256) void ctxln_kernel(const float* __restrict__ X,
                                                    const float* __restrict__ w,
                                                    const float* __restrict__ bias,
                                                    __bf16* __restrict__ out) {
  __shared__ float red[2][4];
  int row = blockIdx.x;
  int t = threadIdx.x;
  const float* xp = X + (size_t)row * 768;
  float v[3];
  float s = 0.f, s2 = 0.f;
#pragma unroll
  for (int i = 0; i < 3; ++i) {
    v[i] = xp[t + i * 256];
    s += v[i];
    s2 += v[i] * v[i];
  }
  int lane = t & 63, wv_ = t >> 6;
#pragma unroll
  for (int off = 32; off > 0; off >>= 1) {
    s += __shfl_down(s, off);
    s2 += __shfl_down(s2, off);
  }
  if (lane == 0) { red[0][wv_] = s; red[1][wv_] = s2; }
  __syncthreads();
  s  = red[0][0] + red[0][1] + red[0][2] + red[0][3];
  s2 = red[1][0] + red[1][1] + red[1][2] + red[1][3];
  float mu = s * (1.0f / 768.0f);
  float var = s2 * (1.0f / 768.0f) - mu * mu;
  float rstd = rsqrtf(var + 1e-5f);
#pragma unroll
  for (int i = 0; i < 3; ++i) {
    int c = t + i * 256;
    out[(size_t)row * 768 + c] = (__bf16)((v[i] - mu) * rstd * w[c] + bias[c]);
  }
}

// ---------------- V transpose (bf16): Vb[b*Ntok+n][h*64+d] -> VT[bh*64+d][n] ----------------
__global__ __launch_bounds__(256) void vtb_kernel(const __bf16* __restrict__ Vb,
                                                  __bf16* __restrict__ VT, int Ntok) {
  __shared__ __bf16 tile[64][68];
  int bh = blockIdx.x, nt = blockIdx.y;
  int b = bh >> 4, h = bh & 15;
  int t = threadIdx.x;
  int tx = t & 15, ty = t >> 4;
#pragma unroll
  for (int i = 0; i < 4; ++i) {
    int n = ty + i * 16;
    bf16x4 v = *(const bf16x4*)(Vb + (size_t)(b * Ntok + nt * 64 + n) * 1024 + h * 64 + tx * 4);
#pragma unroll
    for (int j = 0; j < 4; ++j) tile[n][tx * 4 + j] = v[j];
  }
  __syncthreads();
#pragma unroll
  for (int i = 0; i < 4; ++i) {
    int d = ty + i * 16;
    bf16x4 o;
#pragma unroll
    for (int j = 0; j < 4; ++j) o[j] = tile[tx * 4 + j][d];
    *(bf16x4*)(VT + ((size_t)bh * 64 + d) * Ntok + nt * 64 + tx * 4) = o;
  }
}

// ---------------- pipelined bf16 GEMM BK=32 ----------------
// EPI: 0 fp32; 1 fp32+bias+res; 2 bf16 gelu(acc+bias); 3 fp32 partial at slice z;
//      4 self-QKV (rope Q,K -> Qro/Kro; V -> Vbo bf16)
template <int BM, int BN, int EPI, int DEPTH>
__global__ __launch_bounds__(256) void gemm3(const __bf16* __restrict__ A,
                                             const __bf16* __restrict__ BT,
                                             const float* __restrict__ bias,
                                             const float* __restrict__ res,
                                             void* __restrict__ outv,
                                             int M, int N, int K, int kslices,
                                             const float2* __restrict__ tbl,
                                             __bf16* __restrict__ Qro,
                                             __bf16* __restrict__ Kro,
                                             __bf16* __restrict__ Vbo,
                                             int Ntok) {
  constexpr int MI = BM / 32, NI = BN / 32;
  constexpr int NBUF = DEPTH + 1;
  constexpr int LPT = BM / 64 + BN / 64;
  __shared__ __bf16 sA[NBUF][BM * 32];
  __shared__ __bf16 sB[NBUF][BN * 32];
  const int t = threadIdx.x;
  const int w = t >> 6, lane = t & 63;
  const int lr = lane & 15, lg = lane >> 4;
  const int fxor = (lr >> 1) & 3;
  int nwg = gridDim.x * gridDim.y * gridDim.z;
  int flat = blockIdx.x + gridDim.x * (blockIdx.y + gridDim.y * blockIdx.z);
  flat = (flat & 7) * (nwg >> 3) + (flat >> 3);
  const int bm = flat % gridDim.x;
  int rest = flat / gridDim.x;
  const int bn = rest % gridDim.y;
  const int bz = rest / gridDim.y;
  const int wm = (w >> 1) * (BM / 2), wn = (w & 1) * (BN / 2);
  const int kper = K / kslices;
  const int k0 = bz * kper;
  const int nsteps = kper / 32;
  f32x4 acc[MI][NI] = {};

  auto stage = [&](int buf, int kt) {
#pragma unroll
    for (int i = 0; i < BM / 64; ++i) {
      int e8 = i * 256 + t;
      int row = e8 >> 2, c = e8 & 3;
      int scol = (c ^ ((row >> 1) & 3)) << 3;
      gload16(A + (size_t)(bm * BM + row) * K + kt + scol, &sA[buf][e8 * 8]);
    }
#pragma unroll
    for (int i = 0; i < BN / 64; ++i) {
      int e8 = i * 256 + t;
      int row = e8 >> 2, c = e8 & 3;
      int scol = (c ^ ((row >> 1) & 3)) << 3;
      gload16(BT + (size_t)(bn * BN + row) * K + kt + scol, &sB[buf][e8 * 8]);
    }
  };

  auto compute = [&](int buf) {
    bf16x8 af[MI], bfr[NI];
#pragma unroll
    for (int mi = 0; mi < MI; ++mi)
      af[mi] = *(const bf16x8*)(&sA[buf][(wm + mi * 16 + lr) * 32 + ((lg ^ fxor) << 3)]);
#pragma unroll
    for (int ni = 0; ni < NI; ++ni)
      bfr[ni] = *(const bf16x8*)(&sB[buf][(wn + ni * 16 + lr) * 32 + ((lg ^ fxor) << 3)]);
#pragma unroll
    for (int mi = 0; mi < MI; ++mi)
#pragma unroll
      for (int ni = 0; ni < NI; ++ni)
        acc[mi][ni] = __builtin_amdgcn_mfma_f32_16x16x32_bf16(af[mi], bfr[ni], acc[mi][ni], 0, 0, 0);
  };

#pragma unroll
  for (int i = 0; i < DEPTH; ++i) stage(i, k0 + i * 32);

  int it = 0;
  for (; it < nsteps - (DEPTH - 1); ++it) {
    asm volatile("s_waitcnt vmcnt(%0)" :: "n"((DEPTH - 1) * LPT) : "memory");
    __builtin_amdgcn_s_barrier();
    __builtin_amdgcn_sched_barrier(0);
    if (it + DEPTH < nsteps) stage((it + DEPTH) % NBUF, k0 + (it + DEPTH) * 32);
    compute(it % NBUF);
  }
  asm volatile("s_waitcnt vmcnt(0)" ::: "memory");
  __builtin_amdgcn_s_barrier();
  __builtin_amdgcn_sched_barrier(0);
  for (; it < nsteps; ++it) compute(it % NBUF);

#pragma unroll
  for (int mi = 0; mi < MI; ++mi) {
    int row = bm * BM + wm + mi * 16 + lg * 4;
#pragma unroll
    for (int ni = 0; ni < NI; ++ni) {
      int col = bn * BN + wn + ni * 16 + lr;
#pragma unroll
      for (int r = 0; r < 4; ++r) {
        float v = acc[mi][ni][r];
        int erow = row + r;
        size_t off = (size_t)erow * N + col;
        if (EPI == 0) {
          ((float*)outv)[off] = v;
        } else if (EPI == 1) {
          ((float*)outv)[off] = v + bias[col] + res[off];
        } else if (EPI == 2) {
          ((__bf16*)outv)[off] = (__bf16)fast_gelu(v + bias[col]);
        } else if (EPI == 3) {
          ((float*)outv)[(size_t)bz * M * N + off] = v;
        } else if (EPI == 4) {
          float ov = __shfl_xor(v, 1);
          int b = erow >> 10, n = erow & 1023;
          if (col < 2048) {
            int h = (col >> 6) & 15, dh = col & 63;
            float2 sc = tbl[n * 32 + (dh >> 1)];
            float rv = (lr & 1) ? (ov * sc.x + v * sc.y) : (v * sc.y - ov * sc.x);
            __bf16* dst;
            if (col < 1024) { rv *= 0.125f; dst = Qro; } else dst = Kro;
            dst[((size_t)(b * 16 + h) * Ntok + n) * 64 + dh] = (__bf16)rv;
          } else {
            Vbo[(size_t)erow * 1024 + (col - 2048)] = (__bf16)v;
          }
        }
      }
    }
  }
}

// ---------------- BK=64 probe GEMM: 128x64 tile, fp32 split-K partial epilogue ----------------
// One vmcnt+barrier per 64-wide K-step. LDS: chunk c of row r at c^(r&7) (64-col XOR swizzle).
template <int DEPTH>
__global__ __launch_bounds__(256) void gemm64(const __bf16* __restrict__ A,
                                              const __bf16* __restrict__ BT,
                                              float* __restrict__ outp,
                                              int M, int N, int K, int kslices) {
  constexpr int BM = 128, BN = 64;
  constexpr int NBUF = DEPTH + 1;
  constexpr int LPT = 6;  // 4 A + 2 B gload16 per thread per stage
  __shared__ __bf16 sA[NBUF][BM * 64];
  __shared__ __bf16 sB[NBUF][BN * 64];
  const int t = threadIdx.x;
  const int w = t >> 6, lane = t & 63;
  const int lr = lane & 15, lg = lane >> 4;
  const int sx = lr & 7;
  int nwg = gridDim.x * gridDim.y * gridDim.z;
  int flat = blockIdx.x + gridDim.x * (blockIdx.y + gridDim.y * blockIdx.z);
  flat = (flat & 7) * (nwg >> 3) + (flat >> 3);
  const int bm = flat % gridDim.x;
  int rest = flat / gridDim.x;
  const int bn = rest % gridDim.y;
  const int bz = rest / gridDim.y;
  const int wm = (w >> 1) * 64, wn = (w & 1) * 32;
  const int kper = K / kslices;
  const int k0 = bz * kper;
  const int nsteps = kper / 64;
  f32x4 acc[4][2] = {};

  auto stage = [&](int buf, int kt) {
#pragma unroll
    for (int i = 0; i < 4; ++i) {
      int e8 = i * 256 + t;                  // 1024 chunks: row=e8>>3 (0..127), c=e8&7
      int row = e8 >> 3, c = e8 & 7;
      int scol = (c ^ (row & 7)) << 3;
      gload16(A + (size_t)(bm * BM + row) * K + kt + scol, &sA[buf][e8 * 8]);
    }
#pragma unroll
    for (int i = 0; i < 2; ++i) {
      int e8 = i * 256 + t;                  // 512 chunks: row=e8>>3 (0..63)
      int row = e8 >> 3, c = e8 & 7;
      int scol = (c ^ (row & 7)) << 3;
      gload16(BT + (size_t)(bn * BN + row) * K + kt + scol, &sB[buf][e8 * 8]);
    }
  };

  auto compute = [&](int buf) {
#pragma unroll
    for (int kk = 0; kk < 2; ++kk) {
      bf16x8 af[4], bfr[2];
#pragma unroll
      for (int mi = 0; mi < 4; ++mi)
        af[mi] = *(const bf16x8*)(&sA[buf][(wm + mi * 16 + lr) * 64 + (((kk * 4 + lg) ^ sx) << 3)]);
#pragma unroll
      for (int ni = 0; ni < 2; ++ni)
        bfr[ni] = *(const bf16x8*)(&sB[buf][(wn + ni * 16 + lr) * 64 + (((kk * 4 + lg) ^ sx) << 3)]);
#pragma unroll
      for (int mi = 0; mi < 4; ++mi)
#pragma unroll
        for (int ni = 0; ni < 2; ++ni)
          acc[mi][ni] = __builtin_amdgcn_mfma_f32_16x16x32_bf16(af[mi], bfr[ni], acc[mi][ni], 0, 0, 0);
    }
  };

#pragma unroll
  for (int i = 0; i < DEPTH; ++i) stage(i, k0 + i * 64);

  int it = 0;
  for (; it < nsteps - (DEPTH - 1); ++it) {
    asm volatile("s_waitcnt vmcnt(%0)" :: "n"((DEPTH - 1) * LPT) : "memory");
    __builtin_amdgcn_s_barrier();
    __builtin_amdgcn_sched_barrier(0);
    if (it + DEPTH < nsteps) stage((it + DEPTH) % NBUF, k0 + (it + DEPTH) * 64);
    compute(it % NBUF);
  }
  asm volatile("s_waitcnt vmcnt(0)" ::: "memory");
  __builtin_amdgcn_s_barrier();
  __builtin_amdgcn_sched_barrier(0);
  for (; it < nsteps; ++it) compute(it % NBUF);

#pragma unroll
  for (int mi = 0; mi < 4; ++mi) {
    int row = bm * BM + wm + mi * 16 + lg * 4;
#pragma unroll
    for (int ni = 0; ni < 2; ++ni) {
      int col = bn * BN + wn + ni * 16 + lr;
#pragma unroll
      for (int r = 0; r < 4; ++r)
        outp[(size_t)bz * M * N + (size_t)(row + r) * N + col] = acc[mi][ni][r];
    }
  }
}

// ---------------- fused cross-attn projections: 512 blocks = cq (256) + ckv (256) ----------------
__global__ __launch_bounds__(256) void gemm_cross(const __bf16* __restrict__ Aq,
                                                  const __bf16* __restrict__ Bq,
                                                  const __bf16* __restrict__ Akv,
                                                  const __bf16* __restrict__ Bkv,
                                                  const float2* __restrict__ tbl,
                                                  __bf16* __restrict__ Qro,
                                                  __bf16* __restrict__ Kro,
                                                  __bf16* __restrict__ Vbo) {
  constexpr int BM = 128, BN = 64, DEPTH = 3, NBUF = 4, LPT = 3;
  constexpr int MI = 4, NI = 2;
  __shared__ __bf16 sA[NBUF][BM * 32];
  __shared__ __bf16 sB[NBUF][BN * 32];
  const int t = threadIdx.x;
  const int w = t >> 6, lane = t & 63;
  const int lr = lane & 15, lg = lane >> 4;
  const int fxor = (lr >> 1) & 3;
  int flat = blockIdx.x;
  flat = (flat & 7) * 64 + (flat >> 3);  // bijective XCD swizzle over 512
  const bool isq = flat < 256;
  const __bf16* A  = isq ? Aq : Akv;
  const __bf16* BT = isq ? Bq : Bkv;
  const int K = isq ? 1024 : 768;
  int lf = isq ? flat : flat - 256;
  const int bm = isq ? (lf & 15) : (lf & 7);
  const int bn = isq ? (lf >> 4) : (lf >> 3);
  const int wm = (w >> 1) * 64, wn = (w & 1) * 32;
  const int nsteps = K >> 5;
  f32x4 acc[MI][NI] = {};

  auto stage = [&](int buf, int kt) {
#pragma unroll
    for (int i = 0; i < 2; ++i) {
      int e8 = i * 256 + t;
      int row = e8 >> 2, c = e8 & 3;
      int scol = (c ^ ((row >> 1) & 3)) << 3;
      gload16(A + (size_t)(bm * BM + row) * K + kt + scol, &sA[buf][e8 * 8]);
    }
    {
      int e8 = t;
      int row = e8 >> 2, c = e8 & 3;
      int scol = (c ^ ((row >> 1) & 3)) << 3;
      gload16(BT + (size_t)(bn * BN + row) * K + kt + scol, &sB[buf][e8 * 8]);
    }
  };

  auto compute = [&](int buf) {
    bf16x8 af[MI], bfr[NI];
#pragma unroll
    for (int mi = 0; mi < MI; ++mi)
      af[mi] = *(const bf16x8*)(&sA[buf][(wm + mi * 16 + lr) * 32 + ((lg ^ fxor) << 3)]);
#pragma unroll
    for (int ni = 0; ni < NI; ++ni)
      bfr[ni] = *(const bf16x8*)(&sB[buf][(wn + ni * 16 + lr) * 32 + ((lg ^ fxor) << 3)]);
#pragma unroll
    for (int mi = 0; mi < MI; ++mi)
#pragma unroll
      for (int ni = 0; ni < NI; ++ni)
        acc[mi][ni] = __builtin_amdgcn_mfma_f32_16x16x32_bf16(af[mi], bfr[ni], acc[mi][ni], 0, 0, 0);
  };

#pragma unroll
  for (int i = 0; i < DEPTH; ++i) stage(i, i * 32);

  int it = 0;
  for (; it < nsteps - (DEPTH - 1); ++it) {
    asm volatile("s_waitcnt vmcnt(%0)" :: "n"((DEPTH - 1) * LPT) : "memory");
    __builtin_amdgcn_s_barrier();
    __builtin_amdgcn_sched_barrier(0);
    if (it + DEPTH < nsteps) stage((it + DEPTH) % NBUF, (it + DEPTH) * 32);
    compute(it % NBUF);
  }
  asm volatile("s_waitcnt vmcnt(0)" ::: "memory");
  __builtin_amdgcn_s_barrier();
  __builtin_amdgcn_sched_barrier(0);
  for (; it < nsteps; ++it) compute(it % NBUF);

#pragma unroll
  for (int mi = 0; mi < MI; ++mi) {
    int row = bm * 128 + wm + mi * 16 + lg * 4;
#pragma unroll
    for (int ni = 0; ni < NI; ++ni) {
      int col = bn * 64 + wn + ni * 16 + lr;
#pragma unroll
      for (int r = 0; r < 4; ++r) {
        float v = acc[mi][ni][r];
        int erow = row + r;
        float ov = __shfl_xor(v, 1);
        if (isq) {
          int b = erow >> 10, n = erow & 1023;
          int h = col >> 6, dh = col & 63;
          float2 sc = tbl[n * 32 + (dh >> 1)];
          float rv = ((lr & 1) ? (ov * sc.x + v * sc.y) : (v * sc.y - ov * sc.x)) * 0.125f;
          Qro[((size_t)(b * 16 + h) * 1024 + n) * 64 + dh] = (__bf16)rv;
        } else {
          int b = erow >> 9, n = erow & 511;
          if (col < 1024) {
            int h = col >> 6, dh = col & 63;
            float2 sc = tbl[n * 32 + (dh >> 1)];
            float rv = (lr & 1) ? (ov * sc.x + v * sc.y) : (v * sc.y - ov * sc.x);
            Kro[((size_t)(b * 16 + h) * 512 + n) * 64 + dh] = (__bf16)rv;
          } else {
            Vbo[(size_t)erow * 1024 + (col - 1024)] = (__bf16)v;
          }
        }
      }
    }
  }
}

// ---------------- split-K reduce: out = p0+p1+bias+res (final ff2 only) ----------------
__global__ __launch_bounds__(256) void ff2red_kernel(const float* __restrict__ part,
                                                     const float* __restrict__ bias,
                                                     const float* __restrict__ res,
                                                     float* __restrict__ out, int MN, int N) {
  int idx = blockIdx.x * 256 + threadIdx.x;
  float4 p0 = ((const float4*)part)[idx];
  float4 p1 = ((const float4*)(part + MN))[idx];
  float4 rr = ((const float4*)res)[idx];
  int colb = (idx * 4) & (N - 1);
  float4 bb = *(const float4*)(bias + colb);
  float4 o;
  o.x = p0.x + p1.x + bb.x + rr.x;
  o.y = p0.y + p1.y + bb.y + rr.y;
  o.z = p0.z + p1.z + bb.z + rr.z;
  o.w = p0.w + p1.w + bb.w + rr.w;
  ((float4*)out)[idx] = o;
}

// ---------------- attention, LDS-staged K/V, direct normalized bf16 output ----------------
template <int KITERS>
__global__ __launch_bounds__(256) void attn_kernel(const __bf16* __restrict__ Qr,
                                                   const __bf16* __restrict__ Kr,
                                                   const __bf16* __restrict__ VT,
                                                   __bf16* __restrict__ O,
                                                   int Nq, int Nk) {
  __shared__ __bf16 sK[2][64 * 64];
  __shared__ __bf16 sV[2][64 * 64];
  __shared__ __bf16 Pl[4][16 * 64];
  const int t = threadIdx.x, w = t >> 6, lane = t & 63;
  const int lr = lane & 15, lg = lane >> 4;
  const int lsrc = lane & 48;
  const int swz = (lr & 7) << 3;
  int flat = blockIdx.x + (blockIdx.y << 4);  // grid 16x32
  flat = (flat & 7) * 64 + (flat >> 3);
  const int bh = flat >> 4;
  const int q0 = (flat & 15) * 64 + w * 16;
  const int b = bh >> 4, h = bh & 15;

  auto stage = [&](int buf, int kt) {
#pragma unroll
    for (int i = 0; i < 2; ++i) {
      int e8 = i * 256 + t;
      int row = e8 >> 3, col8 = e8 & 7;
      int scol = (col8 ^ (row & 7)) << 3;
      gload16(Kr + ((size_t)bh * Nk + kt + row) * 64 + scol, &sK[buf][e8 * 8]);
      gload16(VT + ((size_t)bh * 64 + row) * Nk + kt + scol, &sV[buf][e8 * 8]);
    }
  };

  bf16x8 qf[2];
#pragma unroll
  for (int kh = 0; kh < 2; ++kh)
    qf[kh] = *(const bf16x8*)(Qr + ((size_t)bh * Nq + q0 + lr) * 64 + kh * 32 + lg * 8);
  f32x4 accO[4] = {};
  float m = -INFINITY, l = 0.f;

  stage(0, 0);
  __syncthreads();
  int cur = 0;
#pragma unroll
  for (int it = 0; it < KITERS; ++it) {
    if (it + 1 < KITERS) stage(cur ^ 1, (it + 1) * 64);
    f32x4 s[4] = {};
#pragma unroll
    for (int nf = 0; nf < 4; ++nf) {
      int r = nf * 16 + lr;
#pragma unroll
      for (int kh = 0; kh < 2; ++kh) {
        bf16x8 kf = *(const bf16x8*)(&sK[cur][r * 64 + (((kh * 4 + lg) ^ (lr & 7)) << 3)]);
        s[nf] = __builtin_amdgcn_mfma_f32_16x16x32_bf16(kf, qf[kh], s[nf], 0, 0, 0);
      }
    }
    float p[16];
#pragma unroll
    for (int j = 0; j < 16; ++j) p[j] = s[j >> 2][j & 3];
    float pm = p[0];
#pragma unroll
    for (int j = 1; j < 16; ++j) pm = fmaxf(pm, p[j]);
    pm = fmaxf(pm, __shfl_xor(pm, 16));
    pm = fmaxf(pm, __shfl_xor(pm, 32));
    if (!__all(pm <= m + 8.f)) {  // defer-max
      float mnew = fmaxf(m, pm);
      float resc = __expf(m - mnew);
      float rq[4];
#pragma unroll
      for (int r = 0; r < 4; ++r) rq[r] = __shfl(resc, lsrc | (lg * 4 + r));
#pragma unroll
      for (int df = 0; df < 4; ++df)
#pragma unroll
        for (int r = 0; r < 4; ++r) accO[df][r] *= rq[r];
      l *= resc;
      m = mnew;
    }
    float rs = 0.f;
#pragma unroll
    for (int j = 0; j < 16; ++j) { p[j] = __expf(p[j] - m); rs += p[j]; }
    rs += __shfl_xor(rs, 16);
    rs += __shfl_xor(rs, 32);
    l += rs;
#pragma unroll
    for (int nf = 0; nf < 4; ++nf)
#pragma unroll
      for (int jj = 0; jj < 2; ++jj) {
        int k = nf * 16 + lg * 4 + 2 * jj;
        bf16x2 pk;
        pk[0] = (__bf16)p[nf * 4 + 2 * jj];
        pk[1] = (__bf16)p[nf * 4 + 2 * jj + 1];
        *(bf16x2*)(&Pl[w][lr * 64 + (k ^ swz)]) = pk;
      }
    bf16x8 pa0 = *(const bf16x8*)(&Pl[w][lr * 64 + ((lg * 8) ^ swz)]);
    bf16x8 pa1 = *(const bf16x8*)(&Pl[w][lr * 64 + ((32 + lg * 8) ^ swz)]);
#pragma unroll
    for (int df = 0; df < 4; ++df) {
      int d = df * 16 + lr;
      bf16x8 vf0 = *(const bf16x8*)(&sV[cur][d * 64 + ((lg ^ (lr & 7)) << 3)]);
      bf16x8 vf1 = *(const bf16x8*)(&sV[cur][d * 64 + (((4 + lg) ^ (lr & 7)) << 3)]);
      accO[df] = __builtin_amdgcn_mfma_f32_16x16x32_bf16(pa0, vf0, accO[df], 0, 0, 0);
      accO[df] = __builtin_amdgcn_mfma_f32_16x16x32_bf16(pa1, vf1, accO[df], 0, 0, 0);
    }
    __syncthreads();
    cur ^= 1;
  }
  float lq[4];
#pragma unroll
  for (int r = 0; r < 4; ++r) lq[r] = __shfl(l, lsrc | (lg * 4 + r));
#pragma unroll
  for (int r = 0; r < 4; ++r) {
    float inv = 1.0f / lq[r];
    int n = q0 + lg * 4 + r;
#pragma unroll
    for (int df = 0; df < 4; ++df)
      O[(size_t)(b * 1024 + n) * 1024 + h * 64 + df * 16 + lr] = (__bf16)(accO[df][r] * inv);
  }
}

extern "C" void kernel_launch(void* const* d_in, const int* in_sizes, int n_in,
                              void* d_out, int out_size, void* d_ws, size_t ws_size,
                              hipStream_t stream) {
  (void)in_sizes; (void)n_in; (void)out_size; (void)ws_size;
  const float* x       = (const float*)d_in[0];
  const float* cond    = (const float*)d_in[1];
  const float* ctx     = (const float*)d_in[2];
  const float* ln1_w   = (const float*)d_in[3];
  const float* ln1_b   = (const float*)d_in[4];
  const float* g1_w    = (const float*)d_in[5];
  const float* g1_b    = (const float*)d_in[6];
  const float* b1_w    = (const float*)d_in[7];
  const float* b1_b    = (const float*)d_in[8];
  const float* ln2_w   = (const float*)d_in[9];
  const float* ln2_b   = (const float*)d_in[10];
  const float* g2_w    = (const float*)d_in[11];
  const float* g2_b    = (const float*)d_in[12];
  const float* b2_w    = (const float*)d_in[13];
  const float* b2_b    = (const float*)d_in[14];
  const float* sa_wq   = (const float*)d_in[15];
  const float* sa_wkv  = (const float*)d_in[16];
  const float* sa_wo   = (const float*)d_in[17];
  const float* sa_bo   = (const float*)d_in[18];
  const float* ca_lnc_w = (const float*)d_in[19];
  const float* ca_lnc_b = (const float*)d_in[20];
  const float* ca_wq   = (const float*)d_in[21];
  const float* ca_wkv  = (const float*)d_in[22];
  const float* ca_wo   = (const float*)d_in[23];
  const float* ca_bo   = (const float*)d_in[24];
  const float* ff_w1   = (const float*)d_in[25];
  const float* ff_b1   = (const float*)d_in[26];
  const float* ff_w2   = (const float*)d_in[27];
  const float* ff_b2   = (const float*)d_in[28];
  float* out = (float*)d_out;

  char* ws = (char*)d_ws;
  size_t o = 0;
  auto alloc = [&](size_t bytes) {
    void* p = ws + o;
    o += (bytes + 255) & ~(size_t)255;
    return p;
  };

  __bf16* wqT   = (__bf16*)alloc(1024ull * 1024 * 2);  // wqT+wkvT contiguous => BT[3072][1024]
  __bf16* wkvT  = (__bf16*)alloc(2048ull * 1024 * 2);
  __bf16* woT   = (__bf16*)alloc(1024ull * 1024 * 2);
  __bf16* cwqT  = (__bf16*)alloc(1024ull * 1024 * 2);
  __bf16* cwkvT = (__bf16*)alloc(2048ull * 768 * 2);
  __bf16* cwoT  = (__bf16*)alloc(1024ull * 1024 * 2);
  __bf16* ff1T  = (__bf16*)alloc(4096ull * 1024 * 2);
  __bf16* ff2T  = (__bf16*)alloc(1024ull * 4096 * 2);
  float*  mods  = (float*)alloc(4ull * 2 * 1024 * 4);
  float2* tbl   = (float2*)alloc(1024ull * 32 * 8);
  __bf16* ain   = (__bf16*)alloc(2048ull * 1024 * 2);
  float*  Qf    = (float*)alloc(2048ull * 1024 * 4);
  float*  KVf   = (float*)alloc(2048ull * 2048 * 4);
  __bf16* ctxn  = (__bf16*)alloc(1024ull * 768 * 2);
  __bf16* Qr    = (__bf16*)alloc(2048ull * 1024 * 2);
  __bf16* Kr    = (__bf16*)alloc(2048ull * 1024 * 2);
  __bf16* VTb   = (__bf16*)alloc(2048ull * 1024 * 2);
  __bf16* Ob    = (__bf16*)alloc(2048ull * 1024 * 2);
  float*  x1    = (float*)alloc(2048ull * 1024 * 4);
  float*  x2    = (float*)alloc(2048ull * 1024 * 4);
  __bf16* hb    = (__bf16*)KVf;   // FFN hidden (2048x4096 bf16)
  float*  pbuf  = (float*)Qr;     // ff2 split-K partials: 2 x 8MB (Qr..Ob dead in FFN)
  float*  wopb  = (float*)KVf;    // wo split-K partials: 2 x 8MB (KVf free during attn phases)
  float*  mpart = (float*)Qf;     // mod GEMV partials (dead after mod_reduce)
  __bf16* Vb    = (__bf16*)Qf;    // V bf16 token-major (written by QKV/ckv epilogues)

  // ---- fused prep (vectorized 32x128 transposes) ----
  WtDesc wd;
  const float* srcs[8] = {sa_wq, sa_wkv, sa_wo, ca_wq, ca_wkv, ca_wo, ff_w1, ff_w2};
  __bf16* dsts[8] = {wqT, wkvT, woT, cwqT, cwkvT, cwoT, ff1T, ff2T};
  int Ks[8] = {1024, 1024, 1024, 1024, 768, 1024, 1024, 4096};
  int Ns[8] = {1024, 2048, 1024, 1024, 2048, 1024, 4096, 1024};
  int cum = 0;
  for (int i = 0; i < 8; ++i) {
    wd.src[i] = srcs[i]; wd.dst[i] = dsts[i]; wd.K[i] = Ks[i]; wd.N[i] = Ns[i];
    wd.tstart[i] = cum;
    cum += (Ks[i] >> 5) * (Ns[i] >> 7);
  }
  wd.tstart[8] = cum;  // 3968
  prep_kernel<<<cum + 128 + 256, 256, 0, stream>>>(wd, tbl, cond, g1_w, b1_w, g2_w, b2_w, mpart);
  mod_reduce_kernel<<<32, 256, 0, stream>>>(mpart, g1_b, b1_b, g2_b, b2_b, mods);

  // ---- self attention ----
  adaln_kernel<<<2048, 256, 0, stream>>>(x, ln1_w, ln1_b, mods, 0, 1, ain);
  gemm3<128, 64, 4, 3><<<dim3(16, 48), 256, 0, stream>>>(ain, wqT, nullptr, nullptr, nullptr,
                                                         2048, 3072, 1024, 1, tbl, Qr, Kr, Vb, 1024);
  vtb_kernel<<<dim3(32, 16), 256, 0, stream>>>(Vb, VTb, 1024);
  attn_kernel<16><<<dim3(16, 32), 256, 0, stream>>>(Qr, Kr, VTb, Ob, 1024, 1024);
  gemm64<2><<<dim3(16, 16, 2), 256, 0, stream>>>(Ob, woT, wopb, 2048, 1024, 1024, 2);
  red_adaln_kernel<<<2048, 256, 0, stream>>>(wopb, sa_bo, x, ln1_w, ln1_b, mods, 0, 1,
                                             2048 * 1024, x1, ain);

  // ---- cross attention ----
  ctxln_kernel<<<1024, 256, 0, stream>>>(ctx, ca_lnc_w, ca_lnc_b, ctxn);
  gemm_cross<<<512, 256, 0, stream>>>(ain, cwqT, ctxn, cwkvT, tbl, Qr, Kr, Vb);
  vtb_kernel<<<dim3(32, 8), 256, 0, stream>>>(Vb, VTb, 512);
  attn_kernel<8><<<dim3(16, 32), 256, 0, stream>>>(Qr, Kr, VTb, Ob, 1024, 512);
  gemm64<2><<<dim3(16, 16, 2), 256, 0, stream>>>(Ob, cwoT, wopb, 2048, 1024, 1024, 2);
  red_adaln_kernel<<<2048, 256, 0, stream>>>(wopb, ca_bo, x1, ln2_w, ln2_b, mods, 2, 3,
                                             2048 * 1024, x2, ain);

  // ---- FFN ----
  gemm3<128, 128, 2, 2><<<dim3(16, 32), 256, 0, stream>>>(ain, ff1T, ff_b1, nullptr, hb,
                                                          2048, 4096, 1024, 1, nullptr, nullptr, nullptr, nullptr, 0);
  gemm64<2><<<dim3(16, 16, 2), 256, 0, stream>>>(hb, ff2T, pbuf, 2048, 1024, 4096, 2);
  ff2red_kernel<<<2048, 256, 0, stream>>>(pbuf, ff_b2, x2, out, 2048 * 1024, 1024);
}